// Round 7
// baseline (544.268 us; speedup 1.0000x reference)
//
#include <hip/hip_runtime.h>
#include <math.h>

// ---- problem constants ----
static constexpr int kN     = 40000;
static constexpr int kE     = 1000000;
static constexpr int kFIN   = 128;
static constexpr int kHID   = 128;
static constexpr int kTDIM  = 16;
static constexpr int kG     = 64;
static constexpr int kDIN0  = kHID + kTDIM;   // 144
static constexpr int kPOOLC = 16;             // pooling chunks per group
static constexpr int kSCANB = (kN + 255) / 256;  // 157 scan blocks
#define LN_EPS 1e-5f
#define NEG_SLOPE 0.2f

__device__ __forceinline__ float leaky(float v) {
  return v > 0.f ? v : NEG_SLOPE * v;
}

// ---------- weight transpose: wt[k*J + j] = w[j*K + k] (classifier only) ----------
__global__ void k_transpose(const float* __restrict__ w, float* __restrict__ wt,
                            int J, int K) {
  int idx = blockIdx.x * 256 + threadIdx.x;
  if (idx >= J * K) return;
  int j = idx / K, k = idx - j * K;
  wt[k * J + j] = w[idx];
}

// ---------- CSR build ----------
__global__ void __launch_bounds__(256) k_hist(const int* __restrict__ dst, int* __restrict__ deg) {
  int e = blockIdx.x * 256 + threadIdx.x;
  if (e >= kE) return;
  atomicAdd(deg + dst[e], 1);
}

// ---- 3-phase multi-block exclusive scan of deg[0..kN) -> rowptr, cursor ----
__global__ void __launch_bounds__(256) k_scan1(const int* __restrict__ deg,
                                               int* __restrict__ partial) {
  __shared__ int sh[256];
  int t = threadIdx.x;
  int idx = blockIdx.x * 256 + t;
  int v = (idx < kN) ? deg[idx] : 0;
  sh[t] = v;
  __syncthreads();
  for (int off = 128; off >= 1; off >>= 1) {
    if (t < off) sh[t] += sh[t + off];
    __syncthreads();
  }
  if (t == 0) partial[blockIdx.x] = sh[0];
}

__global__ void __launch_bounds__(256) k_scan2(int* __restrict__ partial,
                                               int* __restrict__ rowptr) {
  __shared__ int sh[256];
  int t = threadIdx.x;
  int v = (t < kSCANB) ? partial[t] : 0;
  sh[t] = v;
  __syncthreads();
  for (int off = 1; off < 256; off <<= 1) {
    int add = (t >= off) ? sh[t - off] : 0;
    __syncthreads();
    sh[t] += add;
    __syncthreads();
  }
  if (t < kSCANB) partial[t] = sh[t] - v;        // exclusive offset per block
  if (t == 0) rowptr[kN] = sh[255];              // total
}

__global__ void __launch_bounds__(256) k_scan3(const int* __restrict__ deg,
                                               const int* __restrict__ partial,
                                               int* __restrict__ rowptr,
                                               int* __restrict__ cursor) {
  __shared__ int sh[256];
  int t = threadIdx.x;
  int idx = blockIdx.x * 256 + t;
  int v = (idx < kN) ? deg[idx] : 0;
  sh[t] = v;
  __syncthreads();
  for (int off = 1; off < 256; off <<= 1) {
    int add = (t >= off) ? sh[t - off] : 0;
    __syncthreads();
    sh[t] += add;
    __syncthreads();
  }
  if (idx < kN) {
    int val = partial[blockIdx.x] + sh[t] - v;   // exclusive scan value
    rowptr[idx] = val;
    cursor[idx] = val;
  }
}

__global__ void __launch_bounds__(256) k_scatter(
    const int* __restrict__ src, const int* __restrict__ dst,
    const float* __restrict__ ts, int* __restrict__ cursor,
    int* __restrict__ csr_src, float* __restrict__ csr_ts) {
  int e = blockIdx.x * 256 + threadIdx.x;
  if (e >= kE) return;
  int d = dst[e];
  int pos = atomicAdd(cursor + d, 1);
  csr_src[pos] = src[e];
  csr_ts[pos] = ts[e];
}

// ---------- time encoding gather: h[n,128+j] = sum_{e in(n)} cos(t_e*w[j]+b[j]) ----------
__global__ void __launch_bounds__(256) k_time_gather(
    const int* __restrict__ rowptr, const float* __restrict__ csr_ts,
    const float* __restrict__ tw, const float* __restrict__ tb,
    float* __restrict__ h) {
  int n = blockIdx.x * 4 + (threadIdx.x >> 6);
  if (n >= kN) return;
  int lane = threadIdx.x & 63;
  int j = lane & 15, grp = lane >> 4;
  float w = tw[j], b = tb[j];
  int lo = rowptr[n], hi = rowptr[n + 1];
  float s = 0.f;
  for (int p = lo + grp; p < hi; p += 4) {
    s += cosf(csr_ts[p] * w + b);
  }
  s += __shfl_xor(s, 16);
  s += __shfl_xor(s, 32);
  if (grp == 0) h[(size_t)n * kDIN0 + kHID + j] = s;
}

// ---------- GEMM: out[n,j] = bias[j] + sum_k in[n,k]*w[j,k]  (J=128) ----------
// 16 nodes/block, 8 acc/thread, float4 over k. w is ORIGINAL row-major [128][K].
__global__ void __launch_bounds__(256) k_gemm_f32(
    const float* __restrict__ in, int in_stride, int K,
    const float* __restrict__ w, const float* __restrict__ bias,
    float* __restrict__ out, int out_stride) {
  __shared__ float xs[16 * kDIN0];
  int n0 = blockIdx.x * 16;
  int tid = threadIdx.x;
  int total = 16 * K;
  for (int idx = tid * 4; idx < total; idx += 1024) {
    int nl = idx / K, k = idx - nl * K;
    *(float4*)(xs + idx) = *(const float4*)(in + (size_t)(n0 + nl) * in_stride + k);
  }
  __syncthreads();
  int j = tid & 127, g = tid >> 7;
  const float* wr = w + (size_t)j * K;
  const float* xr = xs + g * (8 * K);
  float acc[8] = {0.f, 0.f, 0.f, 0.f, 0.f, 0.f, 0.f, 0.f};
  for (int k = 0; k < K; k += 4) {
    float4 w4 = *(const float4*)(wr + k);
#pragma unroll
    for (int m = 0; m < 8; ++m) {
      float4 x4 = *(const float4*)(xr + m * K + k);
      acc[m] += w4.x * x4.x + w4.y * x4.y + w4.z * x4.z + w4.w * x4.w;
    }
  }
  float b = bias ? bias[j] : 0.f;
#pragma unroll
  for (int m = 0; m < 8; ++m)
    out[(size_t)(n0 + g * 8 + m) * out_stride + j] = acc[m] + b;
}

// ---------- xh = h @ W.T fused with att dot products (same structure) ----------
__global__ void __launch_bounds__(256) k_xh_att_f32(
    const float* __restrict__ in, int in_stride, int K,
    const float* __restrict__ w,
    const float* __restrict__ att_s, const float* __restrict__ att_d,
    float* __restrict__ xh, float* __restrict__ a_src, float* __restrict__ a_dst) {
  __shared__ float xs[16 * kDIN0];
  int n0 = blockIdx.x * 16;
  int tid = threadIdx.x;
  int total = 16 * K;
  for (int idx = tid * 4; idx < total; idx += 1024) {
    int nl = idx / K, k = idx - nl * K;
    *(float4*)(xs + idx) = *(const float4*)(in + (size_t)(n0 + nl) * in_stride + k);
  }
  __syncthreads();
  int j = tid & 127, g = tid >> 7;
  const float* wr = w + (size_t)j * K;
  const float* xr = xs + g * (8 * K);
  float acc[8] = {0.f, 0.f, 0.f, 0.f, 0.f, 0.f, 0.f, 0.f};
  for (int k = 0; k < K; k += 4) {
    float4 w4 = *(const float4*)(wr + k);
#pragma unroll
    for (int m = 0; m < 8; ++m) {
      float4 x4 = *(const float4*)(xr + m * K + k);
      acc[m] += w4.x * x4.x + w4.y * x4.y + w4.z * x4.z + w4.w * x4.w;
    }
  }
  int hd = j >> 5;
  float as = att_s[j], ad = att_d[j];
#pragma unroll
  for (int m = 0; m < 8; ++m) {
    int n = n0 + g * 8 + m;
    xh[(size_t)n * 128 + j] = acc[m];
    float vs = acc[m] * as, vd = acc[m] * ad;
#pragma unroll
    for (int off = 16; off >= 1; off >>= 1) {
      vs += __shfl_xor(vs, off);
      vd += __shfl_xor(vd, off);
    }
    if ((j & 31) == 0) {
      a_src[n * 4 + hd] = vs;
      a_dst[n * 4 + hd] = vd;
    }
  }
}

// ---------- fused GAT: 1 block (4 waves) per node ----------
// pass 1: block-wide segment max (wave max over edge quarter -> LDS -> block max)
// pass 2: exact softmax gather-accumulate over quarter, partials in LDS
// epilogue: wave 0 combines + bias + LN + ReLU
__global__ void __launch_bounds__(256) k_gat_fused(
    const float* __restrict__ xh, const float* __restrict__ a_src,
    const float* __restrict__ a_dst,
    const int* __restrict__ rowptr, const int* __restrict__ csr_src,
    const float* __restrict__ gb, const float* __restrict__ lw,
    const float* __restrict__ lb, float* __restrict__ out) {
  __shared__ float smax[4][4];
  __shared__ float sden[4][64];
  __shared__ float sa0[4][64];
  __shared__ float sa1[4][64];
  int n = blockIdx.x;
  int wv = threadIdx.x >> 6;
  int lane = threadIdx.x & 63;
  int hd = lane >> 4;        // own head (accumulation), 2 channels per lane
  int ch = lane * 2;
  int hd4 = lane & 3, ed4 = lane >> 2;  // phase-1 mapping: (edge, head)
  float ad4 = a_dst[n * 4 + hd4];

  int lo = rowptr[n], hi = rowptr[n + 1];
  int deg = hi - lo;
  int q0 = lo + (deg * wv) / 4;        // this wave's contiguous quarter
  int q1 = lo + (deg * (wv + 1)) / 4;

  // ---- pass 1: wave max over quarter (self-loop seeded in wave 0) ----
  float mx = (wv == 0 && ed4 == 0) ? leaky(a_src[n * 4 + hd4] + ad4) : -INFINITY;
  for (int p = q0 + ed4; p < q1; p += 16) {
    int s = csr_src[p];
    mx = fmaxf(mx, leaky(a_src[s * 4 + hd4] + ad4));
  }
  // reduce across the 16 lanes sharing hd4 (xor 4,8,16,32 preserve lane&3)
  mx = fmaxf(mx, __shfl_xor(mx, 4));
  mx = fmaxf(mx, __shfl_xor(mx, 8));
  mx = fmaxf(mx, __shfl_xor(mx, 16));
  mx = fmaxf(mx, __shfl_xor(mx, 32));
  if (lane < 4) smax[wv][lane] = mx;
  __syncthreads();
  float m4 = fmaxf(fmaxf(smax[0][hd4], smax[1][hd4]),
                   fmaxf(smax[2][hd4], smax[3][hd4]));

  // ---- pass 2: exp + gather-accumulate ----
  float den = 0.f, acc0 = 0.f, acc1 = 0.f;
  if (wv == 0) {  // self-loop contribution (own head hd)
    float mh = fmaxf(fmaxf(smax[0][hd], smax[1][hd]),
                     fmaxf(smax[2][hd], smax[3][hd]));
    float w_self = __expf(leaky(a_src[n * 4 + hd] + a_dst[n * 4 + hd]) - mh);
    den = w_self;
    float2 xv = *(const float2*)(xh + (size_t)n * 128 + ch);
    acc0 = w_self * xv.x;
    acc1 = w_self * xv.y;
  }
  for (int p = q0; p < q1; ) {
    int cnt = q1 - p;
    cnt = cnt < 16 ? cnt : 16;
    float w4 = 0.f;
    int s4 = 0;
    if (ed4 < cnt) {
      s4 = csr_src[p + ed4];
      w4 = __expf(leaky(a_src[s4 * 4 + hd4] + ad4) - m4);
    }
#pragma unroll 4
    for (int ed = 0; ed < cnt; ++ed) {
      int s = __shfl(s4, ed * 4);
      float wv_ = __shfl(w4, ed * 4 + hd);
      float2 xv = *(const float2*)(xh + (size_t)s * 128 + ch);
      den += wv_;
      acc0 += wv_ * xv.x;
      acc1 += wv_ * xv.y;
    }
    p += cnt;
  }
  sden[wv][lane] = den;
  sa0[wv][lane] = acc0;
  sa1[wv][lane] = acc1;
  __syncthreads();
  if (wv != 0) return;

  // ---- epilogue (wave 0): combine partials + bias + LN + ReLU ----
  den  = sden[0][lane] + sden[1][lane] + sden[2][lane] + sden[3][lane];
  acc0 = sa0[0][lane] + sa0[1][lane] + sa0[2][lane] + sa0[3][lane];
  acc1 = sa1[0][lane] + sa1[1][lane] + sa1[2][lane] + sa1[3][lane];
  float inv = 1.f / den;
  float v0 = acc0 * inv + gb[ch];
  float v1 = acc1 * inv + gb[ch + 1];
  float s = v0 + v1, sq = v0 * v0 + v1 * v1;
#pragma unroll
  for (int off = 32; off >= 1; off >>= 1) {
    s += __shfl_xor(s, off);
    sq += __shfl_xor(sq, off);
  }
  float mean = s * (1.f / 128.f);
  float var = sq * (1.f / 128.f) - mean * mean;
  float rs = rsqrtf(var + LN_EPS);
  float y0 = fmaxf((v0 - mean) * rs * lw[ch] + lb[ch], 0.f);
  float y1 = fmaxf((v1 - mean) * rs * lw[ch + 1] + lb[ch + 1], 0.f);
  float2 o = {y0, y1};
  *(float2*)(out + (size_t)n * 128 + ch) = o;
}

// ---------- pooling stage 1: 64 groups x 16 chunks, partial sum/max ----------
__global__ void __launch_bounds__(128) k_pool1(
    const float* __restrict__ h, const int* __restrict__ batch,
    float* __restrict__ psum, float* __restrict__ pmax) {
  int g = blockIdx.x >> 4, chunk = blockIdx.x & (kPOOLC - 1);
  int c = threadIdx.x;  // 128 channels
  int lo, hi;
  { int a = 0, b = kN; while (a < b) { int m = (a + b) >> 1; if (batch[m] < g) a = m + 1; else b = m; } lo = a; }
  { int a = 0, b = kN; while (a < b) { int m = (a + b) >> 1; if (batch[m] < g + 1) a = m + 1; else b = m; } hi = a; }
  int len = hi - lo;
  int c0 = lo + (int)(((long long)len * chunk) / kPOOLC);
  int c1 = lo + (int)(((long long)len * (chunk + 1)) / kPOOLC);
  float s = 0.f, mx = -INFINITY;
  for (int n = c0; n < c1; ++n) {
    float v = h[(size_t)n * 128 + c];
    s += v;
    mx = fmaxf(mx, v);
  }
  psum[(size_t)blockIdx.x * 128 + c] = s;
  pmax[(size_t)blockIdx.x * 128 + c] = mx;
}

// ---------- pooling stage 2: fold 16 partials, mean divide ----------
__global__ void __launch_bounds__(128) k_pool2(
    const float* __restrict__ psum, const float* __restrict__ pmax,
    const int* __restrict__ batch, float* __restrict__ hg) {
  int g = blockIdx.x;
  int c = threadIdx.x;
  int lo, hi;
  { int a = 0, b = kN; while (a < b) { int m = (a + b) >> 1; if (batch[m] < g) a = m + 1; else b = m; } lo = a; }
  { int a = 0, b = kN; while (a < b) { int m = (a + b) >> 1; if (batch[m] < g + 1) a = m + 1; else b = m; } hi = a; }
  float s = 0.f, mx = -INFINITY;
#pragma unroll
  for (int k = 0; k < kPOOLC; ++k) {
    s += psum[(size_t)(g * kPOOLC + k) * 128 + c];
    mx = fmaxf(mx, pmax[(size_t)(g * kPOOLC + k) * 128 + c]);
  }
  int cnt = hi - lo;
  hg[g * 256 + c] = (cnt > 0) ? s / (float)cnt : 0.f;
  hg[g * 256 + 128 + c] = mx;
}

// ---------- classifier: relu(hg@W1.T+b1)@W2.T+b2 ----------
__global__ void __launch_bounds__(128) k_cls(
    const float* __restrict__ hg, const float* __restrict__ w1t,
    const float* __restrict__ b1, const float* __restrict__ w2,
    const float* __restrict__ b2, float* __restrict__ out) {
  __shared__ float row[256];
  __shared__ float o1[128];
  int g = blockIdx.x, tid = threadIdx.x;  // 128 threads
  row[tid] = hg[g * 256 + tid];
  row[tid + 128] = hg[g * 256 + 128 + tid];
  __syncthreads();
  float s = b1[tid];
  for (int k = 0; k < 256; ++k) s += row[k] * w1t[k * 128 + tid];
  o1[tid] = fmaxf(s, 0.f);
  __syncthreads();
  if (tid < 2) {
    float r = b2[tid];
    for (int j = 0; j < 128; ++j) r += o1[j] * w2[tid * 128 + j];
    out[g * 2 + tid] = r;
  }
}

extern "C" void kernel_launch(void* const* d_in, const int* in_sizes, int n_in,
                              void* d_out, int out_size, void* d_ws, size_t ws_size,
                              hipStream_t stream) {
  const float* x      = (const float*)d_in[0];
  const int*   ei     = (const int*)d_in[1];
  const float* ts     = (const float*)d_in[2];
  const int*   batch  = (const int*)d_in[3];
  const float* time_w = (const float*)d_in[4];
  const float* time_b = (const float*)d_in[5];
  const float* proj_w = (const float*)d_in[6];
  const float* proj_b = (const float*)d_in[7];
  const float* g0w    = (const float*)d_in[8];
  const float* as0    = (const float*)d_in[9];
  const float* ad0    = (const float*)d_in[10];
  const float* g0b    = (const float*)d_in[11];
  const float* ln0w   = (const float*)d_in[12];
  const float* ln0b   = (const float*)d_in[13];
  const float* g1w    = (const float*)d_in[14];
  const float* as1    = (const float*)d_in[15];
  const float* ad1    = (const float*)d_in[16];
  const float* g1b    = (const float*)d_in[17];
  const float* ln1w   = (const float*)d_in[18];
  const float* ln1b   = (const float*)d_in[19];
  const float* c1w    = (const float*)d_in[20];
  const float* c1b    = (const float*)d_in[21];
  const float* c2w    = (const float*)d_in[22];
  const float* c2b    = (const float*)d_in[23];
  float* out = (float*)d_out;

  const int* src = ei;
  const int* dst = ei + kE;

  // ---- workspace layout ----
  float* ws    = (float*)d_ws;
  float* hbuf  = ws;                                 // [N][144] (later reused as [N][128])
  float* xh    = hbuf + (size_t)kN * kDIN0;          // [N][128]
  float* a_src = xh + (size_t)kN * 128;              // [N][4]
  float* a_dst = a_src + kN * 4;                     // [N][4]
  float* c1T   = a_dst + kN * 4;                     // 256x128
  float* hg    = c1T + 256 * 128;                    // [G][256]
  float* csr_ts = hg + kG * 256;                     // [E]
  int* csr_src = (int*)(csr_ts + kE);                // [E]
  int* rowptr  = csr_src + kE;                       // [N+1]
  int* deg     = rowptr + (kN + 1);                  // [N]
  int* cursor  = deg + kN;                           // [N]
  int* partial = cursor + kN;                        // [kSCANB]
  float* psum  = (float*)(partial + kSCANB);         // [G*16][128]
  float* pmax  = psum + kG * kPOOLC * 128;           // [G*16][128]

  // classifier weight transpose (tiny; GEMM kernels use original layouts)
  k_transpose<<<(128 * 256 + 255) / 256, 256, 0, stream>>>(c1w, c1T, 128, 256);

  // ---- CSR build (dst-sorted) ----
  hipMemsetAsync(deg, 0, kN * sizeof(int), stream);
  k_hist<<<(kE + 255) / 256, 256, 0, stream>>>(dst, deg);
  k_scan1<<<kSCANB, 256, 0, stream>>>(deg, partial);
  k_scan2<<<1, 256, 0, stream>>>(partial, rowptr);
  k_scan3<<<kSCANB, 256, 0, stream>>>(deg, partial, rowptr, cursor);
  k_scatter<<<(kE + 255) / 256, 256, 0, stream>>>(src, dst, ts, cursor, csr_src, csr_ts);

  // ---- node projection + time encoding (both direct stores, no memset) ----
  k_gemm_f32<<<kN / 16, 256, 0, stream>>>(x, kFIN, kFIN, proj_w, proj_b, hbuf, kDIN0);
  k_time_gather<<<kN / 4, 256, 0, stream>>>(rowptr, csr_ts, time_w, time_b, hbuf);

  // ---- GAT layer 0 ----
  k_xh_att_f32<<<kN / 16, 256, 0, stream>>>(hbuf, kDIN0, kDIN0, g0w, as0, ad0, xh, a_src, a_dst);
  k_gat_fused<<<kN, 256, 0, stream>>>(xh, a_src, a_dst, rowptr, csr_src,
                                      g0b, ln0w, ln0b, hbuf);  // hbuf now [N][128]

  // ---- GAT layer 1 ----
  k_xh_att_f32<<<kN / 16, 256, 0, stream>>>(hbuf, 128, 128, g1w, as1, ad1, xh, a_src, a_dst);
  k_gat_fused<<<kN, 256, 0, stream>>>(xh, a_src, a_dst, rowptr, csr_src,
                                      g1b, ln1w, ln1b, hbuf);

  // ---- pooling + classifier ----
  k_pool1<<<kG * kPOOLC, 128, 0, stream>>>(hbuf, batch, psum, pmax);
  k_pool2<<<kG, 128, 0, stream>>>(psum, pmax, batch, hg);
  k_cls<<<kG, 128, 0, stream>>>(hg, c1T, c1b, c2w, c2b, out);
}

// Round 8
// 498.000 us; speedup vs baseline: 1.0929x; 1.0929x over previous
//
#include <hip/hip_runtime.h>
#include <math.h>

// ---- problem constants ----
static constexpr int kN     = 40000;
static constexpr int kE     = 1000000;
static constexpr int kFIN   = 128;
static constexpr int kHID   = 128;
static constexpr int kTDIM  = 16;
static constexpr int kG     = 64;
static constexpr int kDIN0  = kHID + kTDIM;   // 144
static constexpr int kPOOLC = 16;             // pooling chunks per group
static constexpr int kSCANB = (kN + 255) / 256;  // 157 scan blocks
#define LN_EPS 1e-5f
#define NEG_SLOPE 0.2f

__device__ __forceinline__ float leaky(float v) {
  return v > 0.f ? v : NEG_SLOPE * v;
}

// round-to-nearest-even f32 -> bf16 (as ushort)
__device__ __forceinline__ unsigned short f2bf(float f) {
  unsigned u = __float_as_uint(f);
  unsigned r = u + 0x7fffu + ((u >> 16) & 1u);
  return (unsigned short)(r >> 16);
}

// ---------- weight transpose: wt[k*J + j] = w[j*K + k] (classifier only) ----------
__global__ void k_transpose(const float* __restrict__ w, float* __restrict__ wt,
                            int J, int K) {
  int idx = blockIdx.x * 256 + threadIdx.x;
  if (idx >= J * K) return;
  int j = idx / K, k = idx - j * K;
  wt[k * J + j] = w[idx];
}

// ---------- CSR build ----------
__global__ void __launch_bounds__(256) k_hist(const int* __restrict__ dst, int* __restrict__ deg) {
  int e = blockIdx.x * 256 + threadIdx.x;
  if (e >= kE) return;
  atomicAdd(deg + dst[e], 1);
}

// ---- 3-phase multi-block exclusive scan of deg[0..kN) -> rowptr, cursor ----
__global__ void __launch_bounds__(256) k_scan1(const int* __restrict__ deg,
                                               int* __restrict__ partial) {
  __shared__ int sh[256];
  int t = threadIdx.x;
  int idx = blockIdx.x * 256 + t;
  int v = (idx < kN) ? deg[idx] : 0;
  sh[t] = v;
  __syncthreads();
  for (int off = 128; off >= 1; off >>= 1) {
    if (t < off) sh[t] += sh[t + off];
    __syncthreads();
  }
  if (t == 0) partial[blockIdx.x] = sh[0];
}

__global__ void __launch_bounds__(256) k_scan2(int* __restrict__ partial,
                                               int* __restrict__ rowptr) {
  __shared__ int sh[256];
  int t = threadIdx.x;
  int v = (t < kSCANB) ? partial[t] : 0;
  sh[t] = v;
  __syncthreads();
  for (int off = 1; off < 256; off <<= 1) {
    int add = (t >= off) ? sh[t - off] : 0;
    __syncthreads();
    sh[t] += add;
    __syncthreads();
  }
  if (t < kSCANB) partial[t] = sh[t] - v;        // exclusive offset per block
  if (t == 0) rowptr[kN] = sh[255];              // total
}

__global__ void __launch_bounds__(256) k_scan3(const int* __restrict__ deg,
                                               const int* __restrict__ partial,
                                               int* __restrict__ rowptr,
                                               int* __restrict__ cursor) {
  __shared__ int sh[256];
  int t = threadIdx.x;
  int idx = blockIdx.x * 256 + t;
  int v = (idx < kN) ? deg[idx] : 0;
  sh[t] = v;
  __syncthreads();
  for (int off = 1; off < 256; off <<= 1) {
    int add = (t >= off) ? sh[t - off] : 0;
    __syncthreads();
    sh[t] += add;
    __syncthreads();
  }
  if (idx < kN) {
    int val = partial[blockIdx.x] + sh[t] - v;   // exclusive scan value
    rowptr[idx] = val;
    cursor[idx] = val;
  }
}

__global__ void __launch_bounds__(256) k_scatter(
    const int* __restrict__ src, const int* __restrict__ dst,
    const float* __restrict__ ts, int* __restrict__ cursor,
    int* __restrict__ csr_src, float* __restrict__ csr_ts) {
  int e = blockIdx.x * 256 + threadIdx.x;
  if (e >= kE) return;
  int d = dst[e];
  int pos = atomicAdd(cursor + d, 1);
  csr_src[pos] = src[e];
  csr_ts[pos] = ts[e];
}

// ---------- time encoding gather: h[n,128+j] = sum_{e in(n)} cos(t_e*w[j]+b[j]) ----------
__global__ void __launch_bounds__(256) k_time_gather(
    const int* __restrict__ rowptr, const float* __restrict__ csr_ts,
    const float* __restrict__ tw, const float* __restrict__ tb,
    float* __restrict__ h) {
  int n = blockIdx.x * 4 + (threadIdx.x >> 6);
  if (n >= kN) return;
  int lane = threadIdx.x & 63;
  int j = lane & 15, grp = lane >> 4;
  float w = tw[j], b = tb[j];
  int lo = rowptr[n], hi = rowptr[n + 1];
  float s = 0.f;
  for (int p = lo + grp; p < hi; p += 4) {
    s += cosf(csr_ts[p] * w + b);
  }
  s += __shfl_xor(s, 16);
  s += __shfl_xor(s, 32);
  if (grp == 0) h[(size_t)n * kDIN0 + kHID + j] = s;
}

// ---------- GEMM: out[n,j] = bias[j] + sum_k in[n,k]*w[j,k]  (J=128) ----------
__global__ void __launch_bounds__(256) k_gemm_f32(
    const float* __restrict__ in, int in_stride, int K,
    const float* __restrict__ w, const float* __restrict__ bias,
    float* __restrict__ out, int out_stride) {
  __shared__ float xs[16 * kDIN0];
  int n0 = blockIdx.x * 16;
  int tid = threadIdx.x;
  int total = 16 * K;
  for (int idx = tid * 4; idx < total; idx += 1024) {
    int nl = idx / K, k = idx - nl * K;
    *(float4*)(xs + idx) = *(const float4*)(in + (size_t)(n0 + nl) * in_stride + k);
  }
  __syncthreads();
  int j = tid & 127, g = tid >> 7;
  const float* wr = w + (size_t)j * K;
  const float* xr = xs + g * (8 * K);
  float acc[8] = {0.f, 0.f, 0.f, 0.f, 0.f, 0.f, 0.f, 0.f};
  for (int k = 0; k < K; k += 4) {
    float4 w4 = *(const float4*)(wr + k);
#pragma unroll
    for (int m = 0; m < 8; ++m) {
      float4 x4 = *(const float4*)(xr + m * K + k);
      acc[m] += w4.x * x4.x + w4.y * x4.y + w4.z * x4.z + w4.w * x4.w;
    }
  }
  float b = bias ? bias[j] : 0.f;
#pragma unroll
  for (int m = 0; m < 8; ++m)
    out[(size_t)(n0 + g * 8 + m) * out_stride + j] = acc[m] + b;
}

// ---------- xh(bf16) = h @ W.T fused with att dot products ----------
__global__ void __launch_bounds__(256) k_xh_att_f32(
    const float* __restrict__ in, int in_stride, int K,
    const float* __restrict__ w,
    const float* __restrict__ att_s, const float* __restrict__ att_d,
    unsigned short* __restrict__ xh, float* __restrict__ a_src,
    float* __restrict__ a_dst) {
  __shared__ float xs[16 * kDIN0];
  int n0 = blockIdx.x * 16;
  int tid = threadIdx.x;
  int total = 16 * K;
  for (int idx = tid * 4; idx < total; idx += 1024) {
    int nl = idx / K, k = idx - nl * K;
    *(float4*)(xs + idx) = *(const float4*)(in + (size_t)(n0 + nl) * in_stride + k);
  }
  __syncthreads();
  int j = tid & 127, g = tid >> 7;
  const float* wr = w + (size_t)j * K;
  const float* xr = xs + g * (8 * K);
  float acc[8] = {0.f, 0.f, 0.f, 0.f, 0.f, 0.f, 0.f, 0.f};
  for (int k = 0; k < K; k += 4) {
    float4 w4 = *(const float4*)(wr + k);
#pragma unroll
    for (int m = 0; m < 8; ++m) {
      float4 x4 = *(const float4*)(xr + m * K + k);
      acc[m] += w4.x * x4.x + w4.y * x4.y + w4.z * x4.z + w4.w * x4.w;
    }
  }
  int hd = j >> 5;
  float as = att_s[j], ad = att_d[j];
#pragma unroll
  for (int m = 0; m < 8; ++m) {
    int n = n0 + g * 8 + m;
    xh[(size_t)n * 128 + j] = f2bf(acc[m]);
    float vs = acc[m] * as, vd = acc[m] * ad;
#pragma unroll
    for (int off = 16; off >= 1; off >>= 1) {
      vs += __shfl_xor(vs, off);
      vd += __shfl_xor(vd, off);
    }
    if ((j & 31) == 0) {
      a_src[n * 4 + hd] = vs;
      a_dst[n * 4 + hd] = vd;
    }
  }
}

// ---------- GAT pass A: mrow[n][h] = leaky(max(a_src over in-nbrs+self) + ad) ----------
// (leaky is monotone, so segment-max commutes with it)
__global__ void __launch_bounds__(256) k_gat_max(
    const float* __restrict__ a_src, const float* __restrict__ a_dst,
    const int* __restrict__ rowptr, const int* __restrict__ csr_src,
    float* __restrict__ mrow) {
  int n = blockIdx.x * 4 + (threadIdx.x >> 6);
  if (n >= kN) return;
  int lane = threadIdx.x & 63;
  int hd4 = lane & 3;
  float mx = a_src[n * 4 + hd4];  // self-loop
  int lo = rowptr[n], hi = rowptr[n + 1];
  for (int p = lo + (lane >> 2); p < hi; p += 16) {
    mx = fmaxf(mx, a_src[csr_src[p] * 4 + hd4]);
  }
  mx = fmaxf(mx, __shfl_xor(mx, 4));
  mx = fmaxf(mx, __shfl_xor(mx, 8));
  mx = fmaxf(mx, __shfl_xor(mx, 16));
  mx = fmaxf(mx, __shfl_xor(mx, 32));
  if (lane < 4) mrow[n * 4 + lane] = leaky(mx + a_dst[n * 4 + lane]);
}

// ---------- GAT pass B: exact-softmax gather (bf16 xh) + bias + LN + ReLU ----------
__global__ void __launch_bounds__(256) k_gat_agg(
    const unsigned short* __restrict__ xh, const float* __restrict__ a_src,
    const float* __restrict__ a_dst, const float* __restrict__ mrow,
    const int* __restrict__ rowptr, const int* __restrict__ csr_src,
    const float* __restrict__ gb, const float* __restrict__ lw,
    const float* __restrict__ lb, float* __restrict__ out) {
  int n = blockIdx.x * 4 + (threadIdx.x >> 6);
  if (n >= kN) return;
  int lane = threadIdx.x & 63;
  int hd = lane >> 4;        // own head (accumulation)
  int ch = lane * 2;         // own 2 channels
  int hd4 = lane & 3, ed4 = lane >> 2;  // phase-1 mapping
  float ad4 = a_dst[n * 4 + hd4];
  float m4 = mrow[n * 4 + hd4];

  const unsigned* xbase = (const unsigned*)xh;  // row s at xbase + s*64, dword/lane

  // self-loop init (own head)
  float den, acc0, acc1;
  {
    float w_self = __expf(leaky(a_src[n * 4 + hd] + a_dst[n * 4 + hd]) - mrow[n * 4 + hd]);
    den = w_self;
    unsigned u = xbase[(size_t)n * 64 + lane];
    acc0 = w_self * __uint_as_float(u << 16);
    acc1 = w_self * __uint_as_float(u & 0xffff0000u);
  }

  int lo = rowptr[n], hi = rowptr[n + 1];
  for (int p = lo; p < hi; ) {
    int cnt = hi - p;
    cnt = cnt < 16 ? cnt : 16;
    float w4 = 0.f;
    int s4 = 0;
    if (ed4 < cnt) {
      s4 = csr_src[p + ed4];
      w4 = __expf(leaky(a_src[s4 * 4 + hd4] + ad4) - m4);
    }
#pragma unroll 4
    for (int ed = 0; ed < cnt; ++ed) {
      int s = __shfl(s4, ed * 4);
      float wv = __shfl(w4, ed * 4 + hd);
      unsigned u = xbase[(size_t)s * 64 + lane];
      float x0 = __uint_as_float(u << 16);
      float x1 = __uint_as_float(u & 0xffff0000u);
      den += wv;
      acc0 += wv * x0;
      acc1 += wv * x1;
    }
    p += cnt;
  }

  float inv = 1.f / den;
  float v0 = acc0 * inv + gb[ch];
  float v1 = acc1 * inv + gb[ch + 1];
  float s = v0 + v1, sq = v0 * v0 + v1 * v1;
#pragma unroll
  for (int off = 32; off >= 1; off >>= 1) {
    s += __shfl_xor(s, off);
    sq += __shfl_xor(sq, off);
  }
  float mean = s * (1.f / 128.f);
  float var = sq * (1.f / 128.f) - mean * mean;
  float rs = rsqrtf(var + LN_EPS);
  float y0 = fmaxf((v0 - mean) * rs * lw[ch] + lb[ch], 0.f);
  float y1 = fmaxf((v1 - mean) * rs * lw[ch + 1] + lb[ch + 1], 0.f);
  float2 o = {y0, y1};
  *(float2*)(out + (size_t)n * 128 + ch) = o;
}

// ---------- pooling stage 1: 64 groups x 16 chunks, partial sum/max ----------
__global__ void __launch_bounds__(128) k_pool1(
    const float* __restrict__ h, const int* __restrict__ batch,
    float* __restrict__ psum, float* __restrict__ pmax) {
  int g = blockIdx.x >> 4, chunk = blockIdx.x & (kPOOLC - 1);
  int c = threadIdx.x;  // 128 channels
  int lo, hi;
  { int a = 0, b = kN; while (a < b) { int m = (a + b) >> 1; if (batch[m] < g) a = m + 1; else b = m; } lo = a; }
  { int a = 0, b = kN; while (a < b) { int m = (a + b) >> 1; if (batch[m] < g + 1) a = m + 1; else b = m; } hi = a; }
  int len = hi - lo;
  int c0 = lo + (int)(((long long)len * chunk) / kPOOLC);
  int c1 = lo + (int)(((long long)len * (chunk + 1)) / kPOOLC);
  float s = 0.f, mx = -INFINITY;
  for (int n = c0; n < c1; ++n) {
    float v = h[(size_t)n * 128 + c];
    s += v;
    mx = fmaxf(mx, v);
  }
  psum[(size_t)blockIdx.x * 128 + c] = s;
  pmax[(size_t)blockIdx.x * 128 + c] = mx;
}

// ---------- pooling stage 2: fold 16 partials, mean divide ----------
__global__ void __launch_bounds__(128) k_pool2(
    const float* __restrict__ psum, const float* __restrict__ pmax,
    const int* __restrict__ batch, float* __restrict__ hg) {
  int g = blockIdx.x;
  int c = threadIdx.x;
  int lo, hi;
  { int a = 0, b = kN; while (a < b) { int m = (a + b) >> 1; if (batch[m] < g) a = m + 1; else b = m; } lo = a; }
  { int a = 0, b = kN; while (a < b) { int m = (a + b) >> 1; if (batch[m] < g + 1) a = m + 1; else b = m; } hi = a; }
  float s = 0.f, mx = -INFINITY;
#pragma unroll
  for (int k = 0; k < kPOOLC; ++k) {
    s += psum[(size_t)(g * kPOOLC + k) * 128 + c];
    mx = fmaxf(mx, pmax[(size_t)(g * kPOOLC + k) * 128 + c]);
  }
  int cnt = hi - lo;
  hg[g * 256 + c] = (cnt > 0) ? s / (float)cnt : 0.f;
  hg[g * 256 + 128 + c] = mx;
}

// ---------- classifier: relu(hg@W1.T+b1)@W2.T+b2 ----------
__global__ void __launch_bounds__(128) k_cls(
    const float* __restrict__ hg, const float* __restrict__ w1t,
    const float* __restrict__ b1, const float* __restrict__ w2,
    const float* __restrict__ b2, float* __restrict__ out) {
  __shared__ float row[256];
  __shared__ float o1[128];
  int g = blockIdx.x, tid = threadIdx.x;  // 128 threads
  row[tid] = hg[g * 256 + tid];
  row[tid + 128] = hg[g * 256 + 128 + tid];
  __syncthreads();
  float s = b1[tid];
  for (int k = 0; k < 256; ++k) s += row[k] * w1t[k * 128 + tid];
  o1[tid] = fmaxf(s, 0.f);
  __syncthreads();
  if (tid < 2) {
    float r = b2[tid];
    for (int j = 0; j < 128; ++j) r += o1[j] * w2[tid * 128 + j];
    out[g * 2 + tid] = r;
  }
}

extern "C" void kernel_launch(void* const* d_in, const int* in_sizes, int n_in,
                              void* d_out, int out_size, void* d_ws, size_t ws_size,
                              hipStream_t stream) {
  const float* x      = (const float*)d_in[0];
  const int*   ei     = (const int*)d_in[1];
  const float* ts     = (const float*)d_in[2];
  const int*   batch  = (const int*)d_in[3];
  const float* time_w = (const float*)d_in[4];
  const float* time_b = (const float*)d_in[5];
  const float* proj_w = (const float*)d_in[6];
  const float* proj_b = (const float*)d_in[7];
  const float* g0w    = (const float*)d_in[8];
  const float* as0    = (const float*)d_in[9];
  const float* ad0    = (const float*)d_in[10];
  const float* g0b    = (const float*)d_in[11];
  const float* ln0w   = (const float*)d_in[12];
  const float* ln0b   = (const float*)d_in[13];
  const float* g1w    = (const float*)d_in[14];
  const float* as1    = (const float*)d_in[15];
  const float* ad1    = (const float*)d_in[16];
  const float* g1b    = (const float*)d_in[17];
  const float* ln1w   = (const float*)d_in[18];
  const float* ln1b   = (const float*)d_in[19];
  const float* c1w    = (const float*)d_in[20];
  const float* c1b    = (const float*)d_in[21];
  const float* c2w    = (const float*)d_in[22];
  const float* c2b    = (const float*)d_in[23];
  float* out = (float*)d_out;

  const int* src = ei;
  const int* dst = ei + kE;

  // ---- workspace layout ----
  float* ws    = (float*)d_ws;
  float* hbuf  = ws;                                 // [N][144] f32 (later reused as [N][128])
  unsigned short* xh = (unsigned short*)(hbuf + (size_t)kN * kDIN0);  // [N][128] bf16
  float* a_src = (float*)(xh + (size_t)kN * 128);    // [N][4]
  float* a_dst = a_src + kN * 4;                     // [N][4]
  float* mrow  = a_dst + kN * 4;                     // [N][4]
  float* c1T   = mrow + kN * 4;                      // 256x128
  float* hg    = c1T + 256 * 128;                    // [G][256]
  float* csr_ts = hg + kG * 256;                     // [E]
  int* csr_src = (int*)(csr_ts + kE);                // [E]
  int* rowptr  = csr_src + kE;                       // [N+1]
  int* deg     = rowptr + (kN + 1);                  // [N]
  int* cursor  = deg + kN;                           // [N]
  int* partial = cursor + kN;                        // [kSCANB]
  float* psum  = (float*)(partial + kSCANB);         // [G*16][128]
  float* pmax  = psum + kG * kPOOLC * 128;           // [G*16][128]

  // classifier weight transpose (tiny; GEMM kernels use original layouts)
  k_transpose<<<(128 * 256 + 255) / 256, 256, 0, stream>>>(c1w, c1T, 128, 256);

  // ---- CSR build (dst-sorted) ----
  hipMemsetAsync(deg, 0, kN * sizeof(int), stream);
  k_hist<<<(kE + 255) / 256, 256, 0, stream>>>(dst, deg);
  k_scan1<<<kSCANB, 256, 0, stream>>>(deg, partial);
  k_scan2<<<1, 256, 0, stream>>>(partial, rowptr);
  k_scan3<<<kSCANB, 256, 0, stream>>>(deg, partial, rowptr, cursor);
  k_scatter<<<(kE + 255) / 256, 256, 0, stream>>>(src, dst, ts, cursor, csr_src, csr_ts);

  // ---- node projection + time encoding (both direct stores, no memset) ----
  k_gemm_f32<<<kN / 16, 256, 0, stream>>>(x, kFIN, kFIN, proj_w, proj_b, hbuf, kDIN0);
  k_time_gather<<<kN / 4, 256, 0, stream>>>(rowptr, csr_ts, time_w, time_b, hbuf);

  // ---- GAT layer 0 ----
  k_xh_att_f32<<<kN / 16, 256, 0, stream>>>(hbuf, kDIN0, kDIN0, g0w, as0, ad0, xh, a_src, a_dst);
  k_gat_max<<<kN / 4, 256, 0, stream>>>(a_src, a_dst, rowptr, csr_src, mrow);
  k_gat_agg<<<kN / 4, 256, 0, stream>>>(xh, a_src, a_dst, mrow, rowptr, csr_src,
                                        g0b, ln0w, ln0b, hbuf);  // hbuf now [N][128]

  // ---- GAT layer 1 ----
  k_xh_att_f32<<<kN / 16, 256, 0, stream>>>(hbuf, 128, 128, g1w, as1, ad1, xh, a_src, a_dst);
  k_gat_max<<<kN / 4, 256, 0, stream>>>(a_src, a_dst, rowptr, csr_src, mrow);
  k_gat_agg<<<kN / 4, 256, 0, stream>>>(xh, a_src, a_dst, mrow, rowptr, csr_src,
                                        g1b, ln1w, ln1b, hbuf);

  // ---- pooling + classifier ----
  k_pool1<<<kG * kPOOLC, 128, 0, stream>>>(hbuf, batch, psum, pmax);
  k_pool2<<<kG, 128, 0, stream>>>(psum, pmax, batch, hg);
  k_cls<<<kG, 128, 0, stream>>>(hg, c1T, c1b, c2w, c2b, out);
}

// Round 9
// 446.634 us; speedup vs baseline: 1.2186x; 1.1150x over previous
//
#include <hip/hip_runtime.h>
#include <math.h>

// ---- problem constants ----
static constexpr int kN     = 40000;
static constexpr int kE     = 1000000;
static constexpr int kFIN   = 128;
static constexpr int kHID   = 128;
static constexpr int kTDIM  = 16;
static constexpr int kG     = 64;
static constexpr int kDIN0  = kHID + kTDIM;   // 144
static constexpr int kPOOLC = 16;             // pooling chunks per group
static constexpr int kSCANB = (kN + 255) / 256;  // 157 scan blocks
#define LN_EPS 1e-5f
#define NEG_SLOPE 0.2f

__device__ __forceinline__ float leaky(float v) {
  return v > 0.f ? v : NEG_SLOPE * v;
}

// round-to-nearest-even f32 -> bf16 (as ushort)
__device__ __forceinline__ unsigned short f2bf(float f) {
  unsigned u = __float_as_uint(f);
  unsigned r = u + 0x7fffu + ((u >> 16) & 1u);
  return (unsigned short)(r >> 16);
}
__device__ __forceinline__ float bflo(unsigned u) { return __uint_as_float(u << 16); }
__device__ __forceinline__ float bfhi(unsigned u) { return __uint_as_float(u & 0xffff0000u); }

// ---------- weight transpose: wt[k*J + j] = w[j*K + k] (classifier only) ----------
__global__ void k_transpose(const float* __restrict__ w, float* __restrict__ wt,
                            int J, int K) {
  int idx = blockIdx.x * 256 + threadIdx.x;
  if (idx >= J * K) return;
  int j = idx / K, k = idx - j * K;
  wt[k * J + j] = w[idx];
}

// ---------- CSR build ----------
__global__ void __launch_bounds__(256) k_hist(const int* __restrict__ dst, int* __restrict__ deg) {
  int e = blockIdx.x * 256 + threadIdx.x;
  if (e >= kE) return;
  atomicAdd(deg + dst[e], 1);
}

// ---- 3-phase multi-block exclusive scan of deg[0..kN) -> rowptr, cursor ----
__global__ void __launch_bounds__(256) k_scan1(const int* __restrict__ deg,
                                               int* __restrict__ partial) {
  __shared__ int sh[256];
  int t = threadIdx.x;
  int idx = blockIdx.x * 256 + t;
  int v = (idx < kN) ? deg[idx] : 0;
  sh[t] = v;
  __syncthreads();
  for (int off = 128; off >= 1; off >>= 1) {
    if (t < off) sh[t] += sh[t + off];
    __syncthreads();
  }
  if (t == 0) partial[blockIdx.x] = sh[0];
}

__global__ void __launch_bounds__(256) k_scan2(int* __restrict__ partial,
                                               int* __restrict__ rowptr) {
  __shared__ int sh[256];
  int t = threadIdx.x;
  int v = (t < kSCANB) ? partial[t] : 0;
  sh[t] = v;
  __syncthreads();
  for (int off = 1; off < 256; off <<= 1) {
    int add = (t >= off) ? sh[t - off] : 0;
    __syncthreads();
    sh[t] += add;
    __syncthreads();
  }
  if (t < kSCANB) partial[t] = sh[t] - v;        // exclusive offset per block
  if (t == 0) rowptr[kN] = sh[255];              // total
}

__global__ void __launch_bounds__(256) k_scan3(const int* __restrict__ deg,
                                               const int* __restrict__ partial,
                                               int* __restrict__ rowptr,
                                               int* __restrict__ cursor) {
  __shared__ int sh[256];
  int t = threadIdx.x;
  int idx = blockIdx.x * 256 + t;
  int v = (idx < kN) ? deg[idx] : 0;
  sh[t] = v;
  __syncthreads();
  for (int off = 1; off < 256; off <<= 1) {
    int add = (t >= off) ? sh[t - off] : 0;
    __syncthreads();
    sh[t] += add;
    __syncthreads();
  }
  if (idx < kN) {
    int val = partial[blockIdx.x] + sh[t] - v;   // exclusive scan value
    rowptr[idx] = val;
    cursor[idx] = val;
  }
}

// ---------- scatter: one packed int2 {src, ts} store per edge ----------
__global__ void __launch_bounds__(256) k_scatter(
    const int* __restrict__ src, const int* __restrict__ dst,
    const float* __restrict__ ts, int* __restrict__ cursor,
    int2* __restrict__ csr) {
  int e = blockIdx.x * 256 + threadIdx.x;
  if (e >= kE) return;
  int d = dst[e];
  int pos = atomicAdd(cursor + d, 1);
  csr[pos] = make_int2(src[e], __float_as_int(ts[e]));
}

// ---------- time encoding gather: h[n,128+j] = sum_{e in(n)} cos(t_e*w[j]+b[j]) ----------
__global__ void __launch_bounds__(256) k_time_gather(
    const int* __restrict__ rowptr, const int2* __restrict__ csr,
    const float* __restrict__ tw, const float* __restrict__ tb,
    float* __restrict__ h) {
  int n = blockIdx.x * 4 + (threadIdx.x >> 6);
  if (n >= kN) return;
  int lane = threadIdx.x & 63;
  int j = lane & 15, grp = lane >> 4;
  float w = tw[j], b = tb[j];
  int lo = rowptr[n], hi = rowptr[n + 1];
  float s = 0.f;
  for (int p = lo + grp; p < hi; p += 4) {
    s += cosf(__int_as_float(csr[p].y) * w + b);
  }
  s += __shfl_xor(s, 16);
  s += __shfl_xor(s, 32);
  if (grp == 0) h[(size_t)n * kDIN0 + kHID + j] = s;
}

// ---------- GEMM: out[n,j] = bias[j] + sum_k in[n,k]*w[j,k]  (J=128) ----------
__global__ void __launch_bounds__(256) k_gemm_f32(
    const float* __restrict__ in, int in_stride, int K,
    const float* __restrict__ w, const float* __restrict__ bias,
    float* __restrict__ out, int out_stride) {
  __shared__ float xs[16 * kDIN0];
  int n0 = blockIdx.x * 16;
  int tid = threadIdx.x;
  int total = 16 * K;
  for (int idx = tid * 4; idx < total; idx += 1024) {
    int nl = idx / K, k = idx - nl * K;
    *(float4*)(xs + idx) = *(const float4*)(in + (size_t)(n0 + nl) * in_stride + k);
  }
  __syncthreads();
  int j = tid & 127, g = tid >> 7;
  const float* wr = w + (size_t)j * K;
  const float* xr = xs + g * (8 * K);
  float acc[8] = {0.f, 0.f, 0.f, 0.f, 0.f, 0.f, 0.f, 0.f};
  for (int k = 0; k < K; k += 4) {
    float4 w4 = *(const float4*)(wr + k);
#pragma unroll
    for (int m = 0; m < 8; ++m) {
      float4 x4 = *(const float4*)(xr + m * K + k);
      acc[m] += w4.x * x4.x + w4.y * x4.y + w4.z * x4.z + w4.w * x4.w;
    }
  }
  float b = bias ? bias[j] : 0.f;
#pragma unroll
  for (int m = 0; m < 8; ++m)
    out[(size_t)(n0 + g * 8 + m) * out_stride + j] = acc[m] + b;
}

// ---------- xh(bf16) = h @ W.T fused with att dot products ----------
__global__ void __launch_bounds__(256) k_xh_att_f32(
    const float* __restrict__ in, int in_stride, int K,
    const float* __restrict__ w,
    const float* __restrict__ att_s, const float* __restrict__ att_d,
    unsigned short* __restrict__ xh, float* __restrict__ a_src,
    float* __restrict__ a_dst) {
  __shared__ float xs[16 * kDIN0];
  int n0 = blockIdx.x * 16;
  int tid = threadIdx.x;
  int total = 16 * K;
  for (int idx = tid * 4; idx < total; idx += 1024) {
    int nl = idx / K, k = idx - nl * K;
    *(float4*)(xs + idx) = *(const float4*)(in + (size_t)(n0 + nl) * in_stride + k);
  }
  __syncthreads();
  int j = tid & 127, g = tid >> 7;
  const float* wr = w + (size_t)j * K;
  const float* xr = xs + g * (8 * K);
  float acc[8] = {0.f, 0.f, 0.f, 0.f, 0.f, 0.f, 0.f, 0.f};
  for (int k = 0; k < K; k += 4) {
    float4 w4 = *(const float4*)(wr + k);
#pragma unroll
    for (int m = 0; m < 8; ++m) {
      float4 x4 = *(const float4*)(xr + m * K + k);
      acc[m] += w4.x * x4.x + w4.y * x4.y + w4.z * x4.z + w4.w * x4.w;
    }
  }
  int hd = j >> 5;
  float as = att_s[j], ad = att_d[j];
#pragma unroll
  for (int m = 0; m < 8; ++m) {
    int n = n0 + g * 8 + m;
    xh[(size_t)n * 128 + j] = f2bf(acc[m]);
    float vs = acc[m] * as, vd = acc[m] * ad;
#pragma unroll
    for (int off = 16; off >= 1; off >>= 1) {
      vs += __shfl_xor(vs, off);
      vd += __shfl_xor(vd, off);
    }
    if ((j & 31) == 0) {
      a_src[n * 4 + hd] = vs;
      a_dst[n * 4 + hd] = vd;
    }
  }
}

// ---------- GAT pass A: mrow[n][h] = leaky(max(a_src over in-nbrs+self) + ad) ----------
__global__ void __launch_bounds__(256) k_gat_max(
    const float* __restrict__ a_src, const float* __restrict__ a_dst,
    const int* __restrict__ rowptr, const int2* __restrict__ csr,
    float* __restrict__ mrow) {
  int n = blockIdx.x * 4 + (threadIdx.x >> 6);
  if (n >= kN) return;
  int lane = threadIdx.x & 63;
  int hd4 = lane & 3;
  float mx = a_src[n * 4 + hd4];  // self-loop
  int lo = rowptr[n], hi = rowptr[n + 1];
  for (int p = lo + (lane >> 2); p < hi; p += 16) {
    mx = fmaxf(mx, a_src[csr[p].x * 4 + hd4]);
  }
  mx = fmaxf(mx, __shfl_xor(mx, 4));
  mx = fmaxf(mx, __shfl_xor(mx, 8));
  mx = fmaxf(mx, __shfl_xor(mx, 16));
  mx = fmaxf(mx, __shfl_xor(mx, 32));
  if (lane < 4) mrow[n * 4 + lane] = leaky(mx + a_dst[n * 4 + lane]);
}

// ---------- GAT pass B: exact-softmax gather + bias + LN + ReLU ----------
// one wave per node; 16 lanes per edge (8 channels each), 4 edges in flight.
// no shuffles in the inner loop; cross-group combine in epilogue.
__global__ void __launch_bounds__(256) k_gat_agg(
    const unsigned short* __restrict__ xh, const float* __restrict__ a_src,
    const float* __restrict__ a_dst, const float* __restrict__ mrow,
    const int* __restrict__ rowptr, const int2* __restrict__ csr,
    const float* __restrict__ gb, const float* __restrict__ lw,
    const float* __restrict__ lb, float* __restrict__ out) {
  int n = blockIdx.x * 4 + (threadIdx.x >> 6);
  if (n >= kN) return;
  int lane = threadIdx.x & 63;
  int eg = lane >> 4;         // edge group (0..3)
  int li = lane & 15;         // lane-in-group; channels li*8..+7
  int hd = li >> 2;           // head of this lane's channels
  float ad = a_dst[n * 4 + hd];
  float m4 = mrow[n * 4 + hd];

  float den = 0.f;
  float a0 = 0.f, a1 = 0.f, a2 = 0.f, a3 = 0.f, a4 = 0.f, a5 = 0.f, a6 = 0.f, a7 = 0.f;

  // self-loop (group 0 only)
  if (eg == 0) {
    float w_self = __expf(leaky(a_src[n * 4 + hd] + ad) - m4);
    den = w_self;
    uint4 u = ((const uint4*)(xh + (size_t)n * 128))[li];
    a0 = w_self * bflo(u.x); a1 = w_self * bfhi(u.x);
    a2 = w_self * bflo(u.y); a3 = w_self * bfhi(u.y);
    a4 = w_self * bflo(u.z); a5 = w_self * bfhi(u.z);
    a6 = w_self * bflo(u.w); a7 = w_self * bfhi(u.w);
  }

  int lo = rowptr[n], hi = rowptr[n + 1];
#pragma unroll 2
  for (int p = lo; p < hi; p += 4) {
    int e = p + eg;
    if (e < hi) {
      int s = csr[e].x;
      float wv = __expf(leaky(a_src[s * 4 + hd] + ad) - m4);
      uint4 u = ((const uint4*)(xh + (size_t)s * 128))[li];
      den += wv;
      a0 += wv * bflo(u.x); a1 += wv * bfhi(u.x);
      a2 += wv * bflo(u.y); a3 += wv * bfhi(u.y);
      a4 += wv * bflo(u.z); a5 += wv * bfhi(u.z);
      a6 += wv * bflo(u.w); a7 += wv * bfhi(u.w);
    }
  }

  // cross-group combine (lanes with same li across eg): xor 16, 32
#pragma unroll
  for (int off = 16; off <= 32; off <<= 1) {
    den += __shfl_xor(den, off);
    a0 += __shfl_xor(a0, off); a1 += __shfl_xor(a1, off);
    a2 += __shfl_xor(a2, off); a3 += __shfl_xor(a3, off);
    a4 += __shfl_xor(a4, off); a5 += __shfl_xor(a5, off);
    a6 += __shfl_xor(a6, off); a7 += __shfl_xor(a7, off);
  }

  float inv = 1.f / den;
  int c0 = li * 8;
  float4 gbl = *(const float4*)(gb + c0);
  float4 gbh = *(const float4*)(gb + c0 + 4);
  float v0 = a0 * inv + gbl.x, v1 = a1 * inv + gbl.y;
  float v2 = a2 * inv + gbl.z, v3 = a3 * inv + gbl.w;
  float v4 = a4 * inv + gbh.x, v5 = a5 * inv + gbh.y;
  float v6 = a6 * inv + gbh.z, v7 = a7 * inv + gbh.w;
  float s = v0 + v1 + v2 + v3 + v4 + v5 + v6 + v7;
  float sq = v0*v0 + v1*v1 + v2*v2 + v3*v3 + v4*v4 + v5*v5 + v6*v6 + v7*v7;
#pragma unroll
  for (int off = 1; off <= 8; off <<= 1) {
    s += __shfl_xor(s, off);
    sq += __shfl_xor(sq, off);
  }
  float mean = s * (1.f / 128.f);
  float var = sq * (1.f / 128.f) - mean * mean;
  float rs = rsqrtf(var + LN_EPS);
  if (eg == 0) {
    float4 lwl = *(const float4*)(lw + c0), lwh = *(const float4*)(lw + c0 + 4);
    float4 lbl = *(const float4*)(lb + c0), lbh = *(const float4*)(lb + c0 + 4);
    float4 o0, o1;
    o0.x = fmaxf((v0 - mean) * rs * lwl.x + lbl.x, 0.f);
    o0.y = fmaxf((v1 - mean) * rs * lwl.y + lbl.y, 0.f);
    o0.z = fmaxf((v2 - mean) * rs * lwl.z + lbl.z, 0.f);
    o0.w = fmaxf((v3 - mean) * rs * lwl.w + lbl.w, 0.f);
    o1.x = fmaxf((v4 - mean) * rs * lwh.x + lbh.x, 0.f);
    o1.y = fmaxf((v5 - mean) * rs * lwh.y + lbh.y, 0.f);
    o1.z = fmaxf((v6 - mean) * rs * lwh.z + lbh.z, 0.f);
    o1.w = fmaxf((v7 - mean) * rs * lwh.w + lbh.w, 0.f);
    *(float4*)(out + (size_t)n * 128 + c0) = o0;
    *(float4*)(out + (size_t)n * 128 + c0 + 4) = o1;
  }
}

// ---------- pooling stage 1: 64 groups x 16 chunks, partial sum/max ----------
__global__ void __launch_bounds__(128) k_pool1(
    const float* __restrict__ h, const int* __restrict__ batch,
    float* __restrict__ psum, float* __restrict__ pmax) {
  int g = blockIdx.x >> 4, chunk = blockIdx.x & (kPOOLC - 1);
  int c = threadIdx.x;  // 128 channels
  int lo, hi;
  { int a = 0, b = kN; while (a < b) { int m = (a + b) >> 1; if (batch[m] < g) a = m + 1; else b = m; } lo = a; }
  { int a = 0, b = kN; while (a < b) { int m = (a + b) >> 1; if (batch[m] < g + 1) a = m + 1; else b = m; } hi = a; }
  int len = hi - lo;
  int c0 = lo + (int)(((long long)len * chunk) / kPOOLC);
  int c1 = lo + (int)(((long long)len * (chunk + 1)) / kPOOLC);
  float s = 0.f, mx = -INFINITY;
  for (int n = c0; n < c1; ++n) {
    float v = h[(size_t)n * 128 + c];
    s += v;
    mx = fmaxf(mx, v);
  }
  psum[(size_t)blockIdx.x * 128 + c] = s;
  pmax[(size_t)blockIdx.x * 128 + c] = mx;
}

// ---------- pooling stage 2 + classifier (fused; one block per group) ----------
__global__ void __launch_bounds__(128) k_pool2_cls(
    const float* __restrict__ psum, const float* __restrict__ pmax,
    const int* __restrict__ batch,
    const float* __restrict__ w1t, const float* __restrict__ b1,
    const float* __restrict__ w2, const float* __restrict__ b2,
    float* __restrict__ out) {
  __shared__ float row[256];
  __shared__ float o1[128];
  int g = blockIdx.x;
  int c = threadIdx.x;
  int lo, hi;
  { int a = 0, b = kN; while (a < b) { int m = (a + b) >> 1; if (batch[m] < g) a = m + 1; else b = m; } lo = a; }
  { int a = 0, b = kN; while (a < b) { int m = (a + b) >> 1; if (batch[m] < g + 1) a = m + 1; else b = m; } hi = a; }
  float s = 0.f, mx = -INFINITY;
#pragma unroll
  for (int k = 0; k < kPOOLC; ++k) {
    s += psum[(size_t)(g * kPOOLC + k) * 128 + c];
    mx = fmaxf(mx, pmax[(size_t)(g * kPOOLC + k) * 128 + c]);
  }
  int cnt = hi - lo;
  row[c] = (cnt > 0) ? s / (float)cnt : 0.f;
  row[c + 128] = mx;
  __syncthreads();
  float t = b1[c];
  for (int k = 0; k < 256; ++k) t += row[k] * w1t[k * 128 + c];
  o1[c] = fmaxf(t, 0.f);
  __syncthreads();
  if (c < 2) {
    float r = b2[c];
    for (int j = 0; j < 128; ++j) r += o1[j] * w2[c * 128 + j];
    out[g * 2 + c] = r;
  }
}

extern "C" void kernel_launch(void* const* d_in, const int* in_sizes, int n_in,
                              void* d_out, int out_size, void* d_ws, size_t ws_size,
                              hipStream_t stream) {
  const float* x      = (const float*)d_in[0];
  const int*   ei     = (const int*)d_in[1];
  const float* ts     = (const float*)d_in[2];
  const int*   batch  = (const int*)d_in[3];
  const float* time_w = (const float*)d_in[4];
  const float* time_b = (const float*)d_in[5];
  const float* proj_w = (const float*)d_in[6];
  const float* proj_b = (const float*)d_in[7];
  const float* g0w    = (const float*)d_in[8];
  const float* as0    = (const float*)d_in[9];
  const float* ad0    = (const float*)d_in[10];
  const float* g0b    = (const float*)d_in[11];
  const float* ln0w   = (const float*)d_in[12];
  const float* ln0b   = (const float*)d_in[13];
  const float* g1w    = (const float*)d_in[14];
  const float* as1    = (const float*)d_in[15];
  const float* ad1    = (const float*)d_in[16];
  const float* g1b    = (const float*)d_in[17];
  const float* ln1w   = (const float*)d_in[18];
  const float* ln1b   = (const float*)d_in[19];
  const float* c1w    = (const float*)d_in[20];
  const float* c1b    = (const float*)d_in[21];
  const float* c2w    = (const float*)d_in[22];
  const float* c2b    = (const float*)d_in[23];
  float* out = (float*)d_out;

  const int* src = ei;
  const int* dst = ei + kE;

  // ---- workspace layout ----
  float* ws    = (float*)d_ws;
  float* hbuf  = ws;                                 // [N][144] f32 (later reused as [N][128])
  unsigned short* xh = (unsigned short*)(hbuf + (size_t)kN * kDIN0);  // [N][128] bf16
  float* a_src = (float*)(xh + (size_t)kN * 128);    // [N][4]
  float* a_dst = a_src + kN * 4;                     // [N][4]
  float* mrow  = a_dst + kN * 4;                     // [N][4]
  float* c1T   = mrow + kN * 4;                      // 256x128
  int2* csr    = (int2*)(c1T + 256 * 128);           // [E] packed {src, ts}
  int* rowptr  = (int*)(csr + kE);                   // [N+1]
  int* deg     = rowptr + (kN + 1);                  // [N]
  int* cursor  = deg + kN;                           // [N]
  int* partial = cursor + kN;                        // [kSCANB]
  float* psum  = (float*)(partial + kSCANB);         // [G*16][128]
  float* pmax  = psum + kG * kPOOLC * 128;           // [G*16][128]

  // classifier weight transpose (tiny; GEMM kernels use original layouts)
  k_transpose<<<(128 * 256 + 255) / 256, 256, 0, stream>>>(c1w, c1T, 128, 256);

  // ---- CSR build (dst-sorted) ----
  hipMemsetAsync(deg, 0, kN * sizeof(int), stream);
  k_hist<<<(kE + 255) / 256, 256, 0, stream>>>(dst, deg);
  k_scan1<<<kSCANB, 256, 0, stream>>>(deg, partial);
  k_scan2<<<1, 256, 0, stream>>>(partial, rowptr);
  k_scan3<<<kSCANB, 256, 0, stream>>>(deg, partial, rowptr, cursor);
  k_scatter<<<(kE + 255) / 256, 256, 0, stream>>>(src, dst, ts, cursor, csr);

  // ---- node projection + time encoding (both direct stores, no memset) ----
  k_gemm_f32<<<kN / 16, 256, 0, stream>>>(x, kFIN, kFIN, proj_w, proj_b, hbuf, kDIN0);
  k_time_gather<<<kN / 4, 256, 0, stream>>>(rowptr, csr, time_w, time_b, hbuf);

  // ---- GAT layer 0 ----
  k_xh_att_f32<<<kN / 16, 256, 0, stream>>>(hbuf, kDIN0, kDIN0, g0w, as0, ad0, xh, a_src, a_dst);
  k_gat_max<<<kN / 4, 256, 0, stream>>>(a_src, a_dst, rowptr, csr, mrow);
  k_gat_agg<<<kN / 4, 256, 0, stream>>>(xh, a_src, a_dst, mrow, rowptr, csr,
                                        g0b, ln0w, ln0b, hbuf);  // hbuf now [N][128]

  // ---- GAT layer 1 ----
  k_xh_att_f32<<<kN / 16, 256, 0, stream>>>(hbuf, 128, 128, g1w, as1, ad1, xh, a_src, a_dst);
  k_gat_max<<<kN / 4, 256, 0, stream>>>(a_src, a_dst, rowptr, csr, mrow);
  k_gat_agg<<<kN / 4, 256, 0, stream>>>(xh, a_src, a_dst, mrow, rowptr, csr,
                                        g1b, ln1w, ln1b, hbuf);

  // ---- pooling + classifier ----
  k_pool1<<<kG * kPOOLC, 128, 0, stream>>>(hbuf, batch, psum, pmax);
  k_pool2_cls<<<kG, 128, 0, stream>>>(psum, pmax, batch, c1T, c1b, c2w, c2b, out);
}

// Round 10
// 357.697 us; speedup vs baseline: 1.5216x; 1.2486x over previous
//
#include <hip/hip_runtime.h>
#include <math.h>

// ---- problem constants ----
static constexpr int kN     = 40000;
static constexpr int kE     = 1000000;
static constexpr int kFIN   = 128;
static constexpr int kHID   = 128;
static constexpr int kTDIM  = 16;
static constexpr int kG     = 64;
static constexpr int kDIN0  = kHID + kTDIM;   // 144
static constexpr int kPOOLC = 16;             // pooling chunks per group
static constexpr int kNB    = (kN + 255) / 256;   // 157 dst buckets (256 nodes each)
static constexpr int kCH    = 2048;               // edges per partition block
static constexpr int kPB    = (kE + kCH - 1) / kCH;  // 489 partition blocks
#define LN_EPS 1e-5f
#define NEG_SLOPE 0.2f

__device__ __forceinline__ float leaky(float v) {
  return v > 0.f ? v : NEG_SLOPE * v;
}

// round-to-nearest-even f32 -> bf16 (as ushort)
__device__ __forceinline__ unsigned short f2bf(float f) {
  unsigned u = __float_as_uint(f);
  unsigned r = u + 0x7fffu + ((u >> 16) & 1u);
  return (unsigned short)(r >> 16);
}
__device__ __forceinline__ float bflo(unsigned u) { return __uint_as_float(u << 16); }
__device__ __forceinline__ float bfhi(unsigned u) { return __uint_as_float(u & 0xffff0000u); }

// ---------- weight transpose: wt[k*J + j] = w[j*K + k] (classifier only) ----------
__global__ void k_transpose(const float* __restrict__ w, float* __restrict__ wt,
                            int J, int K) {
  int idx = blockIdx.x * 256 + threadIdx.x;
  if (idx >= J * K) return;
  int j = idx / K, k = idx - j * K;
  wt[k * J + j] = w[idx];
}

// ---------- CSR build: 2-level bucket partition ----------
// part0: bucket histogram, LDS-aggregated
__global__ void __launch_bounds__(256) k_part0(const int* __restrict__ dst,
                                               int* __restrict__ gbhist) {
  __shared__ int h[kNB];
  int t = threadIdx.x;
  for (int i = t; i < kNB; i += 256) h[i] = 0;
  __syncthreads();
  int base = blockIdx.x * kCH;
#pragma unroll
  for (int i = 0; i < kCH / 256; ++i) {
    int e = base + i * 256 + t;
    if (e < kE) atomicAdd(&h[dst[e] >> 8], 1);
  }
  __syncthreads();
  for (int i = t; i < kNB; i += 256) {
    int c = h[i];
    if (c) atomicAdd(gbhist + i, c);
  }
}

// bprefix: exclusive scan of bucket sizes -> bucketbase[0..kNB], gcursor init
__global__ void __launch_bounds__(256) k_bprefix(const int* __restrict__ gbhist,
                                                 int* __restrict__ bucketbase,
                                                 int* __restrict__ gcursor,
                                                 int* __restrict__ rowptr) {
  __shared__ int sh[256];
  int t = threadIdx.x;
  int v = (t < kNB) ? gbhist[t] : 0;
  sh[t] = v;
  __syncthreads();
  for (int off = 1; off < 256; off <<= 1) {
    int a = (t >= off) ? sh[t - off] : 0;
    __syncthreads();
    sh[t] += a;
    __syncthreads();
  }
  int excl = sh[t] - v;
  if (t <= kNB) bucketbase[t] = excl;   // bucketbase[kNB] == kE
  if (t < kNB) gcursor[t] = excl;
  if (t == 0) rowptr[kN] = kE;
}

// part1: partition edges into bucket-contiguous tmp (wg-aggregated reservations)
// tmp entry: x = src | ((dst&255)<<16)  (src < 65536), y = ts bits
__global__ void __launch_bounds__(256) k_part1(
    const int* __restrict__ src, const int* __restrict__ dst,
    const float* __restrict__ ts, int* __restrict__ gcursor,
    int2* __restrict__ tmp) {
  __shared__ int hist[kNB];
  __shared__ int lbase[kNB];
  int t = threadIdx.x;
  for (int i = t; i < kNB; i += 256) hist[i] = 0;
  __syncthreads();
  int base = blockIdx.x * kCH;
  int bk[8];
  int2 ent[8];
#pragma unroll
  for (int i = 0; i < 8; ++i) {
    int e = base + i * 256 + t;
    if (e < kE) {
      int d = dst[e];
      int b = d >> 8;
      bk[i] = b;
      ent[i] = make_int2(src[e] | ((d & 255) << 16), __float_as_int(ts[e]));
      atomicAdd(&hist[b], 1);
    } else {
      bk[i] = -1;
    }
  }
  __syncthreads();
  for (int i = t; i < kNB; i += 256) {
    int c = hist[i];
    lbase[i] = c ? atomicAdd(gcursor + i, c) : 0;
  }
  __syncthreads();
  for (int i = t; i < kNB; i += 256) hist[i] = 0;
  __syncthreads();
#pragma unroll
  for (int i = 0; i < 8; ++i) {
    if (bk[i] >= 0) {
      int off = atomicAdd(&hist[bk[i]], 1);
      tmp[lbase[bk[i]] + off] = ent[i];
    }
  }
}

// part2: one block per bucket — per-node count+scan in LDS (writes rowptr),
// then scatter to final csr within the bucket's L2-resident window.
__global__ void __launch_bounds__(256) k_part2(
    const int2* __restrict__ tmp, const int* __restrict__ bucketbase,
    int* __restrict__ rowptr, int2* __restrict__ csr) {
  __shared__ int cnt[256];
  __shared__ int sh[256];
  __shared__ int cur[256];
  int b = blockIdx.x;
  int t = threadIdx.x;
  int lo = bucketbase[b], hi = bucketbase[b + 1];
  int nnode = kN - b * 256;
  nnode = nnode < 256 ? nnode : 256;
  cnt[t] = 0;
  __syncthreads();
  for (int p = lo + t; p < hi; p += 256)
    atomicAdd(&cnt[(tmp[p].x >> 16) & 255], 1);
  __syncthreads();
  int v = cnt[t];
  sh[t] = v;
  __syncthreads();
  for (int off = 1; off < 256; off <<= 1) {
    int a = (t >= off) ? sh[t - off] : 0;
    __syncthreads();
    sh[t] += a;
    __syncthreads();
  }
  int nodebase = lo + sh[t] - v;
  if (t < nnode) rowptr[b * 256 + t] = nodebase;
  cur[t] = nodebase;
  __syncthreads();
  for (int p = lo + t; p < hi; p += 256) {
    int2 e = tmp[p];
    int pos = atomicAdd(&cur[(e.x >> 16) & 255], 1);
    csr[pos] = make_int2(e.x & 0xffff, e.y);
  }
}

// ---------- time encoding gather: h[n,128+j] = sum_{e in(n)} cos(t_e*w[j]+b[j]) ----------
__global__ void __launch_bounds__(256) k_time_gather(
    const int* __restrict__ rowptr, const int2* __restrict__ csr,
    const float* __restrict__ tw, const float* __restrict__ tb,
    float* __restrict__ h) {
  int n = blockIdx.x * 4 + (threadIdx.x >> 6);
  if (n >= kN) return;
  int lane = threadIdx.x & 63;
  int j = lane & 15, grp = lane >> 4;
  float w = tw[j], b = tb[j];
  int lo = rowptr[n], hi = rowptr[n + 1];
  float s = 0.f;
  for (int p = lo + grp; p < hi; p += 4) {
    s += cosf(__int_as_float(csr[p].y) * w + b);
  }
  s += __shfl_xor(s, 16);
  s += __shfl_xor(s, 32);
  if (grp == 0) h[(size_t)n * kDIN0 + kHID + j] = s;
}

// ---------- GEMM: out[n,j] = bias[j] + sum_k in[n,k]*w[j,k]  (J=128) ----------
__global__ void __launch_bounds__(256) k_gemm_f32(
    const float* __restrict__ in, int in_stride, int K,
    const float* __restrict__ w, const float* __restrict__ bias,
    float* __restrict__ out, int out_stride) {
  __shared__ float xs[16 * kDIN0];
  int n0 = blockIdx.x * 16;
  int tid = threadIdx.x;
  int total = 16 * K;
  for (int idx = tid * 4; idx < total; idx += 1024) {
    int nl = idx / K, k = idx - nl * K;
    *(float4*)(xs + idx) = *(const float4*)(in + (size_t)(n0 + nl) * in_stride + k);
  }
  __syncthreads();
  int j = tid & 127, g = tid >> 7;
  const float* wr = w + (size_t)j * K;
  const float* xr = xs + g * (8 * K);
  float acc[8] = {0.f, 0.f, 0.f, 0.f, 0.f, 0.f, 0.f, 0.f};
  for (int k = 0; k < K; k += 4) {
    float4 w4 = *(const float4*)(wr + k);
#pragma unroll
    for (int m = 0; m < 8; ++m) {
      float4 x4 = *(const float4*)(xr + m * K + k);
      acc[m] += w4.x * x4.x + w4.y * x4.y + w4.z * x4.z + w4.w * x4.w;
    }
  }
  float b = bias ? bias[j] : 0.f;
#pragma unroll
  for (int m = 0; m < 8; ++m)
    out[(size_t)(n0 + g * 8 + m) * out_stride + j] = acc[m] + b;
}

// ---------- xh(bf16) = h @ W.T fused with att dot products ----------
__global__ void __launch_bounds__(256) k_xh_att_f32(
    const float* __restrict__ in, int in_stride, int K,
    const float* __restrict__ w,
    const float* __restrict__ att_s, const float* __restrict__ att_d,
    unsigned short* __restrict__ xh, float* __restrict__ a_src,
    float* __restrict__ a_dst) {
  __shared__ float xs[16 * kDIN0];
  int n0 = blockIdx.x * 16;
  int tid = threadIdx.x;
  int total = 16 * K;
  for (int idx = tid * 4; idx < total; idx += 1024) {
    int nl = idx / K, k = idx - nl * K;
    *(float4*)(xs + idx) = *(const float4*)(in + (size_t)(n0 + nl) * in_stride + k);
  }
  __syncthreads();
  int j = tid & 127, g = tid >> 7;
  const float* wr = w + (size_t)j * K;
  const float* xr = xs + g * (8 * K);
  float acc[8] = {0.f, 0.f, 0.f, 0.f, 0.f, 0.f, 0.f, 0.f};
  for (int k = 0; k < K; k += 4) {
    float4 w4 = *(const float4*)(wr + k);
#pragma unroll
    for (int m = 0; m < 8; ++m) {
      float4 x4 = *(const float4*)(xr + m * K + k);
      acc[m] += w4.x * x4.x + w4.y * x4.y + w4.z * x4.z + w4.w * x4.w;
    }
  }
  int hd = j >> 5;
  float as = att_s[j], ad = att_d[j];
#pragma unroll
  for (int m = 0; m < 8; ++m) {
    int n = n0 + g * 8 + m;
    xh[(size_t)n * 128 + j] = f2bf(acc[m]);
    float vs = acc[m] * as, vd = acc[m] * ad;
#pragma unroll
    for (int off = 16; off >= 1; off >>= 1) {
      vs += __shfl_xor(vs, off);
      vd += __shfl_xor(vd, off);
    }
    if ((j & 31) == 0) {
      a_src[n * 4 + hd] = vs;
      a_dst[n * 4 + hd] = vd;
    }
  }
}

// ---------- GAT: exact softmax WITHOUT max shift (|score| << 88, no overflow) ----------
// one wave per node; 16 lanes per edge (8 channels each), 4 edges in flight.
__global__ void __launch_bounds__(256) k_gat_agg(
    const unsigned short* __restrict__ xh, const float* __restrict__ a_src,
    const float* __restrict__ a_dst,
    const int* __restrict__ rowptr, const int2* __restrict__ csr,
    const float* __restrict__ gb, const float* __restrict__ lw,
    const float* __restrict__ lb, float* __restrict__ out) {
  int n = blockIdx.x * 4 + (threadIdx.x >> 6);
  if (n >= kN) return;
  int lane = threadIdx.x & 63;
  int eg = lane >> 4;         // edge group (0..3)
  int li = lane & 15;         // lane-in-group; channels li*8..+7
  int hd = li >> 2;           // head of this lane's channels
  float ad = a_dst[n * 4 + hd];

  float den = 0.f;
  float a0 = 0.f, a1 = 0.f, a2 = 0.f, a3 = 0.f, a4 = 0.f, a5 = 0.f, a6 = 0.f, a7 = 0.f;

  // self-loop (group 0 only)
  if (eg == 0) {
    float w_self = __expf(leaky(a_src[n * 4 + hd] + ad));
    den = w_self;
    uint4 u = ((const uint4*)(xh + (size_t)n * 128))[li];
    a0 = w_self * bflo(u.x); a1 = w_self * bfhi(u.x);
    a2 = w_self * bflo(u.y); a3 = w_self * bfhi(u.y);
    a4 = w_self * bflo(u.z); a5 = w_self * bfhi(u.z);
    a6 = w_self * bflo(u.w); a7 = w_self * bfhi(u.w);
  }

  int lo = rowptr[n], hi = rowptr[n + 1];
#pragma unroll 2
  for (int p = lo; p < hi; p += 4) {
    int e = p + eg;
    if (e < hi) {
      int s = csr[e].x;
      float wv = __expf(leaky(a_src[s * 4 + hd] + ad));
      uint4 u = ((const uint4*)(xh + (size_t)s * 128))[li];
      den += wv;
      a0 += wv * bflo(u.x); a1 += wv * bfhi(u.x);
      a2 += wv * bflo(u.y); a3 += wv * bfhi(u.y);
      a4 += wv * bflo(u.z); a5 += wv * bfhi(u.z);
      a6 += wv * bflo(u.w); a7 += wv * bfhi(u.w);
    }
  }

  // cross-group combine (lanes with same li across eg): xor 16, 32
#pragma unroll
  for (int off = 16; off <= 32; off <<= 1) {
    den += __shfl_xor(den, off);
    a0 += __shfl_xor(a0, off); a1 += __shfl_xor(a1, off);
    a2 += __shfl_xor(a2, off); a3 += __shfl_xor(a3, off);
    a4 += __shfl_xor(a4, off); a5 += __shfl_xor(a5, off);
    a6 += __shfl_xor(a6, off); a7 += __shfl_xor(a7, off);
  }

  float inv = 1.f / den;
  int c0 = li * 8;
  float4 gbl = *(const float4*)(gb + c0);
  float4 gbh = *(const float4*)(gb + c0 + 4);
  float v0 = a0 * inv + gbl.x, v1 = a1 * inv + gbl.y;
  float v2 = a2 * inv + gbl.z, v3 = a3 * inv + gbl.w;
  float v4 = a4 * inv + gbh.x, v5 = a5 * inv + gbh.y;
  float v6 = a6 * inv + gbh.z, v7 = a7 * inv + gbh.w;
  float s = v0 + v1 + v2 + v3 + v4 + v5 + v6 + v7;
  float sq = v0*v0 + v1*v1 + v2*v2 + v3*v3 + v4*v4 + v5*v5 + v6*v6 + v7*v7;
#pragma unroll
  for (int off = 1; off <= 8; off <<= 1) {
    s += __shfl_xor(s, off);
    sq += __shfl_xor(sq, off);
  }
  float mean = s * (1.f / 128.f);
  float var = sq * (1.f / 128.f) - mean * mean;
  float rs = rsqrtf(var + LN_EPS);
  if (eg == 0) {
    float4 lwl = *(const float4*)(lw + c0), lwh = *(const float4*)(lw + c0 + 4);
    float4 lbl = *(const float4*)(lb + c0), lbh = *(const float4*)(lb + c0 + 4);
    float4 o0, o1;
    o0.x = fmaxf((v0 - mean) * rs * lwl.x + lbl.x, 0.f);
    o0.y = fmaxf((v1 - mean) * rs * lwl.y + lbl.y, 0.f);
    o0.z = fmaxf((v2 - mean) * rs * lwl.z + lbl.z, 0.f);
    o0.w = fmaxf((v3 - mean) * rs * lwl.w + lbl.w, 0.f);
    o1.x = fmaxf((v4 - mean) * rs * lwh.x + lbh.x, 0.f);
    o1.y = fmaxf((v5 - mean) * rs * lwh.y + lbh.y, 0.f);
    o1.z = fmaxf((v6 - mean) * rs * lwh.z + lbh.z, 0.f);
    o1.w = fmaxf((v7 - mean) * rs * lwh.w + lbh.w, 0.f);
    *(float4*)(out + (size_t)n * 128 + c0) = o0;
    *(float4*)(out + (size_t)n * 128 + c0 + 4) = o1;
  }
}

// ---------- pooling stage 1: 64 groups x 16 chunks, partial sum/max ----------
__global__ void __launch_bounds__(128) k_pool1(
    const float* __restrict__ h, const int* __restrict__ batch,
    float* __restrict__ psum, float* __restrict__ pmax) {
  int g = blockIdx.x >> 4, chunk = blockIdx.x & (kPOOLC - 1);
  int c = threadIdx.x;  // 128 channels
  int lo, hi;
  { int a = 0, b = kN; while (a < b) { int m = (a + b) >> 1; if (batch[m] < g) a = m + 1; else b = m; } lo = a; }
  { int a = 0, b = kN; while (a < b) { int m = (a + b) >> 1; if (batch[m] < g + 1) a = m + 1; else b = m; } hi = a; }
  int len = hi - lo;
  int c0 = lo + (int)(((long long)len * chunk) / kPOOLC);
  int c1 = lo + (int)(((long long)len * (chunk + 1)) / kPOOLC);
  float s = 0.f, mx = -INFINITY;
  for (int n = c0; n < c1; ++n) {
    float v = h[(size_t)n * 128 + c];
    s += v;
    mx = fmaxf(mx, v);
  }
  psum[(size_t)blockIdx.x * 128 + c] = s;
  pmax[(size_t)blockIdx.x * 128 + c] = mx;
}

// ---------- pooling stage 2 + classifier (fused; one block per group) ----------
__global__ void __launch_bounds__(128) k_pool2_cls(
    const float* __restrict__ psum, const float* __restrict__ pmax,
    const int* __restrict__ batch,
    const float* __restrict__ w1t, const float* __restrict__ b1,
    const float* __restrict__ w2, const float* __restrict__ b2,
    float* __restrict__ out) {
  __shared__ float row[256];
  __shared__ float o1[128];
  int g = blockIdx.x;
  int c = threadIdx.x;
  int lo, hi;
  { int a = 0, b = kN; while (a < b) { int m = (a + b) >> 1; if (batch[m] < g) a = m + 1; else b = m; } lo = a; }
  { int a = 0, b = kN; while (a < b) { int m = (a + b) >> 1; if (batch[m] < g + 1) a = m + 1; else b = m; } hi = a; }
  float s = 0.f, mx = -INFINITY;
#pragma unroll
  for (int k = 0; k < kPOOLC; ++k) {
    s += psum[(size_t)(g * kPOOLC + k) * 128 + c];
    mx = fmaxf(mx, pmax[(size_t)(g * kPOOLC + k) * 128 + c]);
  }
  int cnt = hi - lo;
  row[c] = (cnt > 0) ? s / (float)cnt : 0.f;
  row[c + 128] = mx;
  __syncthreads();
  float t = b1[c];
  for (int k = 0; k < 256; ++k) t += row[k] * w1t[k * 128 + c];
  o1[c] = fmaxf(t, 0.f);
  __syncthreads();
  if (c < 2) {
    float r = b2[c];
    for (int j = 0; j < 128; ++j) r += o1[j] * w2[c * 128 + j];
    out[g * 2 + c] = r;
  }
}

extern "C" void kernel_launch(void* const* d_in, const int* in_sizes, int n_in,
                              void* d_out, int out_size, void* d_ws, size_t ws_size,
                              hipStream_t stream) {
  const float* x      = (const float*)d_in[0];
  const int*   ei     = (const int*)d_in[1];
  const float* ts     = (const float*)d_in[2];
  const int*   batch  = (const int*)d_in[3];
  const float* time_w = (const float*)d_in[4];
  const float* time_b = (const float*)d_in[5];
  const float* proj_w = (const float*)d_in[6];
  const float* proj_b = (const float*)d_in[7];
  const float* g0w    = (const float*)d_in[8];
  const float* as0    = (const float*)d_in[9];
  const float* ad0    = (const float*)d_in[10];
  const float* g0b    = (const float*)d_in[11];
  const float* ln0w   = (const float*)d_in[12];
  const float* ln0b   = (const float*)d_in[13];
  const float* g1w    = (const float*)d_in[14];
  const float* as1    = (const float*)d_in[15];
  const float* ad1    = (const float*)d_in[16];
  const float* g1b    = (const float*)d_in[17];
  const float* ln1w   = (const float*)d_in[18];
  const float* ln1b   = (const float*)d_in[19];
  const float* c1w    = (const float*)d_in[20];
  const float* c1b    = (const float*)d_in[21];
  const float* c2w    = (const float*)d_in[22];
  const float* c2b    = (const float*)d_in[23];
  float* out = (float*)d_out;

  const int* src = ei;
  const int* dst = ei + kE;

  // ---- workspace layout ----
  float* ws    = (float*)d_ws;
  float* hbuf  = ws;                                 // [N][144] f32 (later reused as [N][128])
  unsigned short* xh = (unsigned short*)(hbuf + (size_t)kN * kDIN0);  // [N][128] bf16
  float* a_src = (float*)(xh + (size_t)kN * 128);    // [N][4]
  float* a_dst = a_src + kN * 4;                     // [N][4]
  float* c1T   = a_dst + kN * 4;                     // 256x128
  int2* csr    = (int2*)(c1T + 256 * 128);           // [E] final {src, ts}
  int2* tmp    = csr + kE;                           // [E] bucket-partitioned
  int* rowptr  = (int*)(tmp + kE);                   // [N+1]
  int* gbhist  = rowptr + (kN + 1);                  // [kNB]
  int* bucketbase = gbhist + kNB;                    // [kNB+1]
  int* gcursor = bucketbase + kNB + 1;               // [kNB]
  float* psum  = (float*)(gcursor + kNB);            // [G*16][128]
  float* pmax  = psum + kG * kPOOLC * 128;           // [G*16][128]

  // classifier weight transpose (tiny; GEMM kernels use original layouts)
  k_transpose<<<(128 * 256 + 255) / 256, 256, 0, stream>>>(c1w, c1T, 128, 256);

  // ---- CSR build: bucket partition ----
  hipMemsetAsync(gbhist, 0, kNB * sizeof(int), stream);
  k_part0<<<kPB, 256, 0, stream>>>(dst, gbhist);
  k_bprefix<<<1, 256, 0, stream>>>(gbhist, bucketbase, gcursor, rowptr);
  k_part1<<<kPB, 256, 0, stream>>>(src, dst, ts, gcursor, tmp);
  k_part2<<<kNB, 256, 0, stream>>>(tmp, bucketbase, rowptr, csr);

  // ---- node projection + time encoding (both direct stores, no memset) ----
  k_gemm_f32<<<kN / 16, 256, 0, stream>>>(x, kFIN, kFIN, proj_w, proj_b, hbuf, kDIN0);
  k_time_gather<<<kN / 4, 256, 0, stream>>>(rowptr, csr, time_w, time_b, hbuf);

  // ---- GAT layer 0 ----
  k_xh_att_f32<<<kN / 16, 256, 0, stream>>>(hbuf, kDIN0, kDIN0, g0w, as0, ad0, xh, a_src, a_dst);
  k_gat_agg<<<kN / 4, 256, 0, stream>>>(xh, a_src, a_dst, rowptr, csr,
                                        g0b, ln0w, ln0b, hbuf);  // hbuf now [N][128]

  // ---- GAT layer 1 ----
  k_xh_att_f32<<<kN / 16, 256, 0, stream>>>(hbuf, 128, 128, g1w, as1, ad1, xh, a_src, a_dst);
  k_gat_agg<<<kN / 4, 256, 0, stream>>>(xh, a_src, a_dst, rowptr, csr,
                                        g1b, ln1w, ln1b, hbuf);

  // ---- pooling + classifier ----
  k_pool1<<<kG * kPOOLC, 128, 0, stream>>>(hbuf, batch, psum, pmax);
  k_pool2_cls<<<kG, 128, 0, stream>>>(psum, pmax, batch, c1T, c1b, c2w, c2b, out);
}

// Round 11
// 285.573 us; speedup vs baseline: 1.9059x; 1.2526x over previous
//
#include <hip/hip_runtime.h>
#include <math.h>

// ---- problem constants ----
static constexpr int kN     = 40000;
static constexpr int kE     = 1000000;
static constexpr int kTDIM  = 16;
static constexpr int kG     = 64;
static constexpr int kPOOLC = 16;             // pooling chunks per group
static constexpr int kNB    = (kN + 255) / 256;   // 157 dst buckets (256 nodes each)
static constexpr int kCH    = 2048;               // edges per partition block
static constexpr int kPB    = (kE + kCH - 1) / kCH;  // 489 partition blocks
#define LN_EPS 1e-5f
#define NEG_SLOPE 0.2f

typedef __attribute__((ext_vector_type(8))) short bf16x8;
typedef __attribute__((ext_vector_type(4))) float f32x4;

__device__ __forceinline__ float leaky(float v) {
  return v > 0.f ? v : NEG_SLOPE * v;
}

// round-to-nearest-even f32 -> bf16 (as ushort)
__device__ __forceinline__ unsigned short f2bf(float f) {
  unsigned u = __float_as_uint(f);
  unsigned r = u + 0x7fffu + ((u >> 16) & 1u);
  return (unsigned short)(r >> 16);
}
__device__ __forceinline__ float bflo(unsigned u) { return __uint_as_float(u << 16); }
__device__ __forceinline__ float bfhi(unsigned u) { return __uint_as_float(u & 0xffff0000u); }

// ---------- weight transpose: wt[k*J + j] = w[j*K + k] (classifier only) ----------
__global__ void k_transpose(const float* __restrict__ w, float* __restrict__ wt,
                            int J, int K) {
  int idx = blockIdx.x * 256 + threadIdx.x;
  if (idx >= J * K) return;
  int j = idx / K, k = idx - j * K;
  wt[k * J + j] = w[idx];
}

// ---------- f32 -> bf16 converters ----------
__global__ void __launch_bounds__(256) k_x2bf(const float* __restrict__ in,
                                              unsigned short* __restrict__ out,
                                              int total4) {
  int i = blockIdx.x * 256 + threadIdx.x;
  if (i >= total4) return;
  float4 v = *(const float4*)(in + (size_t)i * 4);
  ushort4 o = {f2bf(v.x), f2bf(v.y), f2bf(v.z), f2bf(v.w)};
  *(ushort4*)(out + (size_t)i * 4) = o;
}

// weight -> bf16 with K padding (pad with zeros)
__global__ void k_w2bf(const float* __restrict__ w, unsigned short* __restrict__ o,
                       int J, int Kin, int Kpad) {
  int idx = blockIdx.x * 256 + threadIdx.x;
  if (idx >= J * Kpad) return;
  int j = idx / Kpad, k = idx - j * Kpad;
  o[idx] = (k < Kin) ? f2bf(w[j * Kin + k]) : (unsigned short)0;
}

// ---------- CSR build: 2-level bucket partition ----------
__global__ void __launch_bounds__(256) k_part0(const int* __restrict__ dst,
                                               int* __restrict__ gbhist) {
  __shared__ int h[kNB];
  int t = threadIdx.x;
  for (int i = t; i < kNB; i += 256) h[i] = 0;
  __syncthreads();
  int base = blockIdx.x * kCH;
#pragma unroll
  for (int i = 0; i < kCH / 256; ++i) {
    int e = base + i * 256 + t;
    if (e < kE) atomicAdd(&h[dst[e] >> 8], 1);
  }
  __syncthreads();
  for (int i = t; i < kNB; i += 256) {
    int c = h[i];
    if (c) atomicAdd(gbhist + i, c);
  }
}

__global__ void __launch_bounds__(256) k_bprefix(const int* __restrict__ gbhist,
                                                 int* __restrict__ bucketbase,
                                                 int* __restrict__ gcursor,
                                                 int* __restrict__ rowptr) {
  __shared__ int sh[256];
  int t = threadIdx.x;
  int v = (t < kNB) ? gbhist[t] : 0;
  sh[t] = v;
  __syncthreads();
  for (int off = 1; off < 256; off <<= 1) {
    int a = (t >= off) ? sh[t - off] : 0;
    __syncthreads();
    sh[t] += a;
    __syncthreads();
  }
  int excl = sh[t] - v;
  if (t <= kNB) bucketbase[t] = excl;
  if (t < kNB) gcursor[t] = excl;
  if (t == 0) rowptr[kN] = kE;
}

__global__ void __launch_bounds__(256) k_part1(
    const int* __restrict__ src, const int* __restrict__ dst,
    const float* __restrict__ ts, int* __restrict__ gcursor,
    int2* __restrict__ tmp) {
  __shared__ int hist[kNB];
  __shared__ int lbase[kNB];
  int t = threadIdx.x;
  for (int i = t; i < kNB; i += 256) hist[i] = 0;
  __syncthreads();
  int base = blockIdx.x * kCH;
  int bk[8];
  int2 ent[8];
#pragma unroll
  for (int i = 0; i < 8; ++i) {
    int e = base + i * 256 + t;
    if (e < kE) {
      int d = dst[e];
      int b = d >> 8;
      bk[i] = b;
      ent[i] = make_int2(src[e] | ((d & 255) << 16), __float_as_int(ts[e]));
      atomicAdd(&hist[b], 1);
    } else {
      bk[i] = -1;
    }
  }
  __syncthreads();
  for (int i = t; i < kNB; i += 256) {
    int c = hist[i];
    lbase[i] = c ? atomicAdd(gcursor + i, c) : 0;
  }
  __syncthreads();
  for (int i = t; i < kNB; i += 256) hist[i] = 0;
  __syncthreads();
#pragma unroll
  for (int i = 0; i < 8; ++i) {
    if (bk[i] >= 0) {
      int off = atomicAdd(&hist[bk[i]], 1);
      tmp[lbase[bk[i]] + off] = ent[i];
    }
  }
}

__global__ void __launch_bounds__(256) k_part2(
    const int2* __restrict__ tmp, const int* __restrict__ bucketbase,
    int* __restrict__ rowptr, int2* __restrict__ csr) {
  __shared__ int cnt[256];
  __shared__ int sh[256];
  __shared__ int cur[256];
  int b = blockIdx.x;
  int t = threadIdx.x;
  int lo = bucketbase[b], hi = bucketbase[b + 1];
  int nnode = kN - b * 256;
  nnode = nnode < 256 ? nnode : 256;
  cnt[t] = 0;
  __syncthreads();
  for (int p = lo + t; p < hi; p += 256)
    atomicAdd(&cnt[(tmp[p].x >> 16) & 255], 1);
  __syncthreads();
  int v = cnt[t];
  sh[t] = v;
  __syncthreads();
  for (int off = 1; off < 256; off <<= 1) {
    int a = (t >= off) ? sh[t - off] : 0;
    __syncthreads();
    sh[t] += a;
    __syncthreads();
  }
  int nodebase = lo + sh[t] - v;
  if (t < nnode) rowptr[b * 256 + t] = nodebase;
  cur[t] = nodebase;
  __syncthreads();
  for (int p = lo + t; p < hi; p += 256) {
    int2 e = tmp[p];
    int pos = atomicAdd(&cur[(e.x >> 16) & 255], 1);
    csr[pos] = make_int2(e.x & 0xffff, e.y);
  }
}

// ---------- time encoding gather: hb16[n,128+j] = bf16(sum cos(t*w[j]+b[j])) ----------
__global__ void __launch_bounds__(256) k_time_gather(
    const int* __restrict__ rowptr, const int2* __restrict__ csr,
    const float* __restrict__ tw, const float* __restrict__ tb,
    unsigned short* __restrict__ hb) {
  int n = blockIdx.x * 4 + (threadIdx.x >> 6);
  if (n >= kN) return;
  int lane = threadIdx.x & 63;
  int j = lane & 15, grp = lane >> 4;
  float w = tw[j], b = tb[j];
  int lo = rowptr[n], hi = rowptr[n + 1];
  float s = 0.f;
  for (int p = lo + grp; p < hi; p += 4) {
    s += cosf(__int_as_float(csr[p].y) * w + b);
  }
  s += __shfl_xor(s, 16);
  s += __shfl_xor(s, 32);
  if (grp == 0) hb[(size_t)n * 160 + 128 + j] = f2bf(s);
}

// ---------- MFMA projection: hb16[n, 0..127] = bf16(xb16 @ pw^T + bias) ----------
// block = 16 nodes, 4 waves; wave w handles j-tiles {2w, 2w+1}. K = 128.
__global__ void __launch_bounds__(256) k_mfma_proj(
    const unsigned short* __restrict__ xb, const unsigned short* __restrict__ wb,
    const float* __restrict__ bias, unsigned short* __restrict__ outb) {
  int n0 = blockIdx.x * 16;
  int wv = threadIdx.x >> 6, l = threadIdx.x & 63;
  int lr = l & 15, lk = l >> 4;
  const int K = 128;
  int jt0 = 2 * wv, jt1 = 2 * wv + 1;
  const unsigned short* arow = xb + (size_t)(n0 + lr) * K + lk * 8;
  const unsigned short* brow0 = wb + (size_t)(jt0 * 16 + lr) * K + lk * 8;
  const unsigned short* brow1 = wb + (size_t)(jt1 * 16 + lr) * K + lk * 8;
  f32x4 acc0 = {0.f, 0.f, 0.f, 0.f}, acc1 = {0.f, 0.f, 0.f, 0.f};
#pragma unroll
  for (int c = 0; c < 4; ++c) {
    bf16x8 a = *(const bf16x8*)(arow + c * 32);
    acc0 = __builtin_amdgcn_mfma_f32_16x16x32_bf16(a, *(const bf16x8*)(brow0 + c * 32), acc0, 0, 0, 0);
    acc1 = __builtin_amdgcn_mfma_f32_16x16x32_bf16(a, *(const bf16x8*)(brow1 + c * 32), acc1, 0, 0, 0);
  }
  int j0 = jt0 * 16 + lr, j1 = jt1 * 16 + lr;
  float bb0 = bias[j0], bb1 = bias[j1];
#pragma unroll
  for (int r = 0; r < 4; ++r) {
    int node = n0 + lk * 4 + r;
    outb[(size_t)node * 160 + j0] = f2bf(acc0[r] + bb0);
    outb[(size_t)node * 160 + j1] = f2bf(acc1[r] + bb1);
  }
}

// ---------- MFMA xh = h @ W^T (bf16 in/out) fused with att dots ----------
// wave w covers head w (j in [32w, 32w+32)); D row=(l>>4)*4+r, col=l&15.
__global__ void __launch_bounds__(256) k_mfma_xh_att(
    const unsigned short* __restrict__ hb, int K,
    const unsigned short* __restrict__ wb,
    const float* __restrict__ att_s, const float* __restrict__ att_d,
    unsigned short* __restrict__ xh, float* __restrict__ a_src,
    float* __restrict__ a_dst) {
  int n0 = blockIdx.x * 16;
  int wv = threadIdx.x >> 6, l = threadIdx.x & 63;
  int lr = l & 15, lk = l >> 4;
  int jt0 = 2 * wv, jt1 = 2 * wv + 1;
  const unsigned short* arow = hb + (size_t)(n0 + lr) * K + lk * 8;
  const unsigned short* brow0 = wb + (size_t)(jt0 * 16 + lr) * K + lk * 8;
  const unsigned short* brow1 = wb + (size_t)(jt1 * 16 + lr) * K + lk * 8;
  f32x4 acc0 = {0.f, 0.f, 0.f, 0.f}, acc1 = {0.f, 0.f, 0.f, 0.f};
  int nch = K >> 5;
  for (int c = 0; c < nch; ++c) {
    bf16x8 a = *(const bf16x8*)(arow + c * 32);
    acc0 = __builtin_amdgcn_mfma_f32_16x16x32_bf16(a, *(const bf16x8*)(brow0 + c * 32), acc0, 0, 0, 0);
    acc1 = __builtin_amdgcn_mfma_f32_16x16x32_bf16(a, *(const bf16x8*)(brow1 + c * 32), acc1, 0, 0, 0);
  }
  int j0 = jt0 * 16 + lr, j1 = jt1 * 16 + lr;
  float as0 = att_s[j0], as1 = att_s[j1];
  float ad0 = att_d[j0], ad1 = att_d[j1];
#pragma unroll
  for (int r = 0; r < 4; ++r) {
    int node = n0 + lk * 4 + r;
    float d0 = acc0[r], d1 = acc1[r];
    xh[(size_t)node * 128 + j0] = f2bf(d0);
    xh[(size_t)node * 128 + j1] = f2bf(d1);
    float vs = d0 * as0 + d1 * as1;
    float vd = d0 * ad0 + d1 * ad1;
    vs += __shfl_xor(vs, 1); vs += __shfl_xor(vs, 2);
    vs += __shfl_xor(vs, 4); vs += __shfl_xor(vs, 8);
    vd += __shfl_xor(vd, 1); vd += __shfl_xor(vd, 2);
    vd += __shfl_xor(vd, 4); vd += __shfl_xor(vd, 8);
    if (lr == 0) {
      a_src[node * 4 + wv] = vs;
      a_dst[node * 4 + wv] = vd;
    }
  }
}

// ---------- GAT: exact softmax without max shift + bias + LN + ReLU, bf16 out ----------
__global__ void __launch_bounds__(256) k_gat_agg(
    const unsigned short* __restrict__ xh, const float* __restrict__ a_src,
    const float* __restrict__ a_dst,
    const int* __restrict__ rowptr, const int2* __restrict__ csr,
    const float* __restrict__ gb, const float* __restrict__ lw,
    const float* __restrict__ lb, unsigned short* __restrict__ outb) {
  int n = blockIdx.x * 4 + (threadIdx.x >> 6);
  if (n >= kN) return;
  int lane = threadIdx.x & 63;
  int eg = lane >> 4;         // edge group (0..3)
  int li = lane & 15;         // lane-in-group; channels li*8..+7
  int hd = li >> 2;           // head of this lane's channels
  float ad = a_dst[n * 4 + hd];

  float den = 0.f;
  float a0 = 0.f, a1 = 0.f, a2 = 0.f, a3 = 0.f, a4 = 0.f, a5 = 0.f, a6 = 0.f, a7 = 0.f;

  if (eg == 0) {
    float w_self = __expf(leaky(a_src[n * 4 + hd] + ad));
    den = w_self;
    uint4 u = ((const uint4*)(xh + (size_t)n * 128))[li];
    a0 = w_self * bflo(u.x); a1 = w_self * bfhi(u.x);
    a2 = w_self * bflo(u.y); a3 = w_self * bfhi(u.y);
    a4 = w_self * bflo(u.z); a5 = w_self * bfhi(u.z);
    a6 = w_self * bflo(u.w); a7 = w_self * bfhi(u.w);
  }

  int lo = rowptr[n], hi = rowptr[n + 1];
#pragma unroll 2
  for (int p = lo; p < hi; p += 4) {
    int e = p + eg;
    if (e < hi) {
      int s = csr[e].x;
      float wv = __expf(leaky(a_src[s * 4 + hd] + ad));
      uint4 u = ((const uint4*)(xh + (size_t)s * 128))[li];
      den += wv;
      a0 += wv * bflo(u.x); a1 += wv * bfhi(u.x);
      a2 += wv * bflo(u.y); a3 += wv * bfhi(u.y);
      a4 += wv * bflo(u.z); a5 += wv * bfhi(u.z);
      a6 += wv * bflo(u.w); a7 += wv * bfhi(u.w);
    }
  }

#pragma unroll
  for (int off = 16; off <= 32; off <<= 1) {
    den += __shfl_xor(den, off);
    a0 += __shfl_xor(a0, off); a1 += __shfl_xor(a1, off);
    a2 += __shfl_xor(a2, off); a3 += __shfl_xor(a3, off);
    a4 += __shfl_xor(a4, off); a5 += __shfl_xor(a5, off);
    a6 += __shfl_xor(a6, off); a7 += __shfl_xor(a7, off);
  }

  float inv = 1.f / den;
  int c0 = li * 8;
  float4 gbl = *(const float4*)(gb + c0);
  float4 gbh = *(const float4*)(gb + c0 + 4);
  float v0 = a0 * inv + gbl.x, v1 = a1 * inv + gbl.y;
  float v2 = a2 * inv + gbl.z, v3 = a3 * inv + gbl.w;
  float v4 = a4 * inv + gbh.x, v5 = a5 * inv + gbh.y;
  float v6 = a6 * inv + gbh.z, v7 = a7 * inv + gbh.w;
  float s = v0 + v1 + v2 + v3 + v4 + v5 + v6 + v7;
  float sq = v0*v0 + v1*v1 + v2*v2 + v3*v3 + v4*v4 + v5*v5 + v6*v6 + v7*v7;
#pragma unroll
  for (int off = 1; off <= 8; off <<= 1) {
    s += __shfl_xor(s, off);
    sq += __shfl_xor(sq, off);
  }
  float mean = s * (1.f / 128.f);
  float var = sq * (1.f / 128.f) - mean * mean;
  float rs = rsqrtf(var + LN_EPS);
  if (eg == 0) {
    float4 lwl = *(const float4*)(lw + c0), lwh = *(const float4*)(lw + c0 + 4);
    float4 lbl = *(const float4*)(lb + c0), lbh = *(const float4*)(lb + c0 + 4);
    float y0 = fmaxf((v0 - mean) * rs * lwl.x + lbl.x, 0.f);
    float y1 = fmaxf((v1 - mean) * rs * lwl.y + lbl.y, 0.f);
    float y2 = fmaxf((v2 - mean) * rs * lwl.z + lbl.z, 0.f);
    float y3 = fmaxf((v3 - mean) * rs * lwl.w + lbl.w, 0.f);
    float y4 = fmaxf((v4 - mean) * rs * lwh.x + lbh.x, 0.f);
    float y5 = fmaxf((v5 - mean) * rs * lwh.y + lbh.y, 0.f);
    float y6 = fmaxf((v6 - mean) * rs * lwh.z + lbh.z, 0.f);
    float y7 = fmaxf((v7 - mean) * rs * lwh.w + lbh.w, 0.f);
    uint4 o;
    o.x = (unsigned)f2bf(y0) | ((unsigned)f2bf(y1) << 16);
    o.y = (unsigned)f2bf(y2) | ((unsigned)f2bf(y3) << 16);
    o.z = (unsigned)f2bf(y4) | ((unsigned)f2bf(y5) << 16);
    o.w = (unsigned)f2bf(y6) | ((unsigned)f2bf(y7) << 16);
    *(uint4*)(outb + (size_t)n * 128 + c0) = o;
  }
}

// ---------- pooling stage 1 (bf16 input): 64 groups x 16 chunks ----------
__global__ void __launch_bounds__(128) k_pool1(
    const unsigned short* __restrict__ h, const int* __restrict__ batch,
    float* __restrict__ psum, float* __restrict__ pmax) {
  int g = blockIdx.x >> 4, chunk = blockIdx.x & (kPOOLC - 1);
  int c = threadIdx.x;  // 128 channels
  int lo, hi;
  { int a = 0, b = kN; while (a < b) { int m = (a + b) >> 1; if (batch[m] < g) a = m + 1; else b = m; } lo = a; }
  { int a = 0, b = kN; while (a < b) { int m = (a + b) >> 1; if (batch[m] < g + 1) a = m + 1; else b = m; } hi = a; }
  int len = hi - lo;
  int c0 = lo + (int)(((long long)len * chunk) / kPOOLC);
  int c1 = lo + (int)(((long long)len * (chunk + 1)) / kPOOLC);
  float s = 0.f, mx = -INFINITY;
  for (int n = c0; n < c1; ++n) {
    float v = __uint_as_float(((unsigned)h[(size_t)n * 128 + c]) << 16);
    s += v;
    mx = fmaxf(mx, v);
  }
  psum[(size_t)blockIdx.x * 128 + c] = s;
  pmax[(size_t)blockIdx.x * 128 + c] = mx;
}

// ---------- pooling stage 2 + classifier (fused; one block per group) ----------
__global__ void __launch_bounds__(128) k_pool2_cls(
    const float* __restrict__ psum, const float* __restrict__ pmax,
    const int* __restrict__ batch,
    const float* __restrict__ w1t, const float* __restrict__ b1,
    const float* __restrict__ w2, const float* __restrict__ b2,
    float* __restrict__ out) {
  __shared__ float row[256];
  __shared__ float o1[128];
  int g = blockIdx.x;
  int c = threadIdx.x;
  int lo, hi;
  { int a = 0, b = kN; while (a < b) { int m = (a + b) >> 1; if (batch[m] < g) a = m + 1; else b = m; } lo = a; }
  { int a = 0, b = kN; while (a < b) { int m = (a + b) >> 1; if (batch[m] < g + 1) a = m + 1; else b = m; } hi = a; }
  float s = 0.f, mx = -INFINITY;
#pragma unroll
  for (int k = 0; k < kPOOLC; ++k) {
    s += psum[(size_t)(g * kPOOLC + k) * 128 + c];
    mx = fmaxf(mx, pmax[(size_t)(g * kPOOLC + k) * 128 + c]);
  }
  int cnt = hi - lo;
  row[c] = (cnt > 0) ? s / (float)cnt : 0.f;
  row[c + 128] = mx;
  __syncthreads();
  float t = b1[c];
  for (int k = 0; k < 256; ++k) t += row[k] * w1t[k * 128 + c];
  o1[c] = fmaxf(t, 0.f);
  __syncthreads();
  if (c < 2) {
    float r = b2[c];
    for (int j = 0; j < 128; ++j) r += o1[j] * w2[c * 128 + j];
    out[g * 2 + c] = r;
  }
}

extern "C" void kernel_launch(void* const* d_in, const int* in_sizes, int n_in,
                              void* d_out, int out_size, void* d_ws, size_t ws_size,
                              hipStream_t stream) {
  const float* x      = (const float*)d_in[0];
  const int*   ei     = (const int*)d_in[1];
  const float* ts     = (const float*)d_in[2];
  const int*   batch  = (const int*)d_in[3];
  const float* time_w = (const float*)d_in[4];
  const float* time_b = (const float*)d_in[5];
  const float* proj_w = (const float*)d_in[6];
  const float* proj_b = (const float*)d_in[7];
  const float* g0w    = (const float*)d_in[8];
  const float* as0    = (const float*)d_in[9];
  const float* ad0    = (const float*)d_in[10];
  const float* g0b    = (const float*)d_in[11];
  const float* ln0w   = (const float*)d_in[12];
  const float* ln0b   = (const float*)d_in[13];
  const float* g1w    = (const float*)d_in[14];
  const float* as1    = (const float*)d_in[15];
  const float* ad1    = (const float*)d_in[16];
  const float* g1b    = (const float*)d_in[17];
  const float* ln1w   = (const float*)d_in[18];
  const float* ln1b   = (const float*)d_in[19];
  const float* c1w    = (const float*)d_in[20];
  const float* c1b    = (const float*)d_in[21];
  const float* c2w    = (const float*)d_in[22];
  const float* c2b    = (const float*)d_in[23];
  float* out = (float*)d_out;

  const int* src = ei;
  const int* dst = ei + kE;

  // ---- workspace layout (bytes; all large regions 16B-aligned) ----
  char* p = (char*)d_ws;
  unsigned short* xh   = (unsigned short*)p; p += (size_t)kN * 128 * 2;  // xh; aliased as xb16 early
  unsigned short* hb16 = (unsigned short*)p; p += (size_t)kN * 160 * 2;  // layer-0 input (padded K=160)
  unsigned short* h1b16= (unsigned short*)p; p += (size_t)kN * 128 * 2;  // gat outputs (bf16)
  float* a_src = (float*)p; p += (size_t)kN * 4 * 4;
  float* a_dst = (float*)p; p += (size_t)kN * 4 * 4;
  unsigned short* pwb = (unsigned short*)p; p += 128 * 128 * 2;
  unsigned short* w0b = (unsigned short*)p; p += 128 * 160 * 2;
  unsigned short* w1b = (unsigned short*)p; p += 128 * 128 * 2;
  float* c1T = (float*)p; p += 256 * 128 * 4;
  int2* csr = (int2*)p; p += (size_t)kE * 8;
  int2* tmp = (int2*)p; p += (size_t)kE * 8;
  float* psum = (float*)p; p += (size_t)kG * kPOOLC * 128 * 4;
  float* pmax = (float*)p; p += (size_t)kG * kPOOLC * 128 * 4;
  int* rowptr = (int*)p; p += (kN + 1) * 4;
  int* gbhist = (int*)p; p += kNB * 4;
  int* bucketbase = (int*)p; p += (kNB + 1) * 4;
  int* gcursor = (int*)p; p += kNB * 4;
  unsigned short* xb16 = xh;  // alias: dead before xh is first written

  // classifier weight transpose + weight bf16 conversion (tiny)
  k_transpose<<<(128 * 256 + 255) / 256, 256, 0, stream>>>(c1w, c1T, 128, 256);
  k_w2bf<<<(128 * 128 + 255) / 256, 256, 0, stream>>>(proj_w, pwb, 128, 128, 128);
  k_w2bf<<<(128 * 160 + 255) / 256, 256, 0, stream>>>(g0w, w0b, 128, 144, 160);
  k_w2bf<<<(128 * 128 + 255) / 256, 256, 0, stream>>>(g1w, w1b, 128, 128, 128);

  // ---- CSR build: bucket partition ----
  hipMemsetAsync(gbhist, 0, kNB * sizeof(int), stream);
  k_part0<<<kPB, 256, 0, stream>>>(dst, gbhist);
  k_bprefix<<<1, 256, 0, stream>>>(gbhist, bucketbase, gcursor, rowptr);
  k_part1<<<kPB, 256, 0, stream>>>(src, dst, ts, gcursor, tmp);
  k_part2<<<kNB, 256, 0, stream>>>(tmp, bucketbase, rowptr, csr);

  // ---- x -> bf16, projection (MFMA) + time encoding into hb16 ----
  k_x2bf<<<(kN * 128 / 4 + 255) / 256, 256, 0, stream>>>(x, xb16, kN * 128 / 4);
  hipMemsetAsync(hb16, 0, (size_t)kN * 160 * 2, stream);  // zero pad cols 144..159
  k_mfma_proj<<<kN / 16, 256, 0, stream>>>(xb16, pwb, proj_b, hb16);
  k_time_gather<<<kN / 4, 256, 0, stream>>>(rowptr, csr, time_w, time_b, hb16);

  // ---- GAT layer 0 ----
  k_mfma_xh_att<<<kN / 16, 256, 0, stream>>>(hb16, 160, w0b, as0, ad0, xh, a_src, a_dst);
  k_gat_agg<<<kN / 4, 256, 0, stream>>>(xh, a_src, a_dst, rowptr, csr,
                                        g0b, ln0w, ln0b, h1b16);

  // ---- GAT layer 1 ----
  k_mfma_xh_att<<<kN / 16, 256, 0, stream>>>(h1b16, 128, w1b, as1, ad1, xh, a_src, a_dst);
  k_gat_agg<<<kN / 4, 256, 0, stream>>>(xh, a_src, a_dst, rowptr, csr,
                                        g1b, ln1w, ln1b, h1b16);

  // ---- pooling + classifier ----
  k_pool1<<<kG * kPOOLC, 128, 0, stream>>>(h1b16, batch, psum, pmax);
  k_pool2_cls<<<kG, 128, 0, stream>>>(psum, pmax, batch, c1T, c1b, c2w, c2b, out);
}